// Round 10
// baseline (421.817 us; speedup 1.0000x reference)
//
#include <hip/hip_runtime.h>
#include <hip/hip_fp16.h>
#include <stdint.h>

// Transformer-XL relative attention, round 10: swapped-S + shifted-BD with
// LDS Wt round-trip for PV (bisect of r9's failing register-exchange).
// L=qlen=klen=1024, BATCH=4, NH=16, DH=64, DM=1024.
//
// Structure (main path; one head-i-tile per block, 4 waves, wave owns
// j-range [w*256,(w+1)*256)):
//  - S^T via mfma(K, Q): lane (lg,lr) holds S for i=lr, j = chunk*16+lg*4+r2.
//    BD gather = ONE ds_read_b64; mask = one u32.
//  - BD stored ALREADY REL-SHIFTED (verified numerically vs the HW-proven
//    map): build double-writes BDp[i'][c] -> BD[i'][c+i0+i'-1023] (t<=0) and
//    BD[i'-1][c+i0+i'+1] (t>=2); row16 VALU -> BD[15][c+i0+17]; diagonal
//    BD[i][i0+i+1] pre-zeroed (t==1).
//  - PV A-frag via per-wave LDS Wt (r7/r8-proven mechanism): write ushort4,
//    read b128. In-wave ds ordering only; no barriers in the j-loop.
//  - LDS ~39.4KB -> __launch_bounds__(256,4): 4 blocks/CU.
// MFMA frag convention (verified r3-8): A/B row|col=lane&15, k=(lane>>4)*8+e;
// D col=lane&15, row=(lane>>4)*4+reg.

#define L 1024
#define BATCH 4
#define NH 16
#define DH 64
#define DM 1024
#define TI 16
#define NJT 16
#define BD_ST 1028          // fp16 elems per BD row (8B-aligned rows, +4 banks/row)
#define BDP_ST 1032         // legacy kernels
#define WT_ST 40            // Wt row stride (shorts): 80B rows, 16B-aligned
#define SCALE 0.125f
#define CS 0.18033688011112042f   // 0.125 * log2(e)

typedef __attribute__((ext_vector_type(8))) short short8;
typedef __attribute__((ext_vector_type(4))) float f32x4;

static __device__ __forceinline__ unsigned short f2bf(float f) {
    union { float f; unsigned int u; } x; x.f = f;
    return (unsigned short)((x.u + 0x7fffu + ((x.u >> 16) & 1u)) >> 16);  // RNE
}
static __device__ __forceinline__ float bf2f(unsigned short h) {
    union { unsigned int u; float f; } x; x.u = ((unsigned int)h) << 16;
    return x.f;
}
static __device__ __forceinline__ unsigned short f2h(float f) {
    __half h = __float2half(f);
    union { __half h; unsigned short s; } x; x.h = h; return x.s;
}
static __device__ __forceinline__ float h2f(unsigned short s) {
    union { __half h; unsigned short s; } x; x.s = s; return __half2float(x.h);
}
static __device__ __forceinline__ unsigned short* usp(void* base, int byteoff) {
    return (unsigned short*)((char*)base + byteoff);
}
static __device__ __forceinline__ short8 ld8(const void* base, int byteoff) {
    return *(const short8*)((const char*)base + byteoff);
}
static __device__ __forceinline__ float fexp2(float x) {
#if __has_builtin(__builtin_amdgcn_exp2f)
    return __builtin_amdgcn_exp2f(x);
#else
    return __expf(x * 0.6931471805599453f);
#endif
}
#define SW128(row, colByte) ((((row) * 128) + (colByte)) ^ (((row) & 7) << 4))

// ---------------------------------------------------------------------------
// K1a (main): rh = r @ Wr^T + br via bf16 MFMA -> rhb [n][c][d] bf16.
// ---------------------------------------------------------------------------
__global__ __launch_bounds__(256) void rh_gemm_mfma(
    const float* __restrict__ r, const float* __restrict__ Wr,
    const float* __restrict__ br, unsigned short* __restrict__ rhb)
{
    __shared__ unsigned short rT[64 * 64];
    __shared__ unsigned short wT[64 * 64];
    const int c0 = blockIdx.x * 64, m0 = blockIdx.y * 64;
    const int tid = threadIdx.x;
    const int w = tid >> 6, lane = tid & 63, lr = lane & 15, lg = lane >> 4;
    f32x4 acc[4] = {};

    for (int kt = 0; kt < 16; ++kt) {
        const int k0 = kt * 64;
        __syncthreads();
        const int row = tid >> 2, cb = (tid & 3) * 16;
#pragma unroll
        for (int q4 = 0; q4 < 4; ++q4) {
            float4 rv = *(const float4*)(r + (size_t)(c0 + row) * DM + k0 + cb + q4 * 4);
            unsigned short* p = usp(rT, SW128(row, (cb + q4 * 4) * 2));
            p[0] = f2bf(rv.x); p[1] = f2bf(rv.y); p[2] = f2bf(rv.z); p[3] = f2bf(rv.w);
            float4 wv = *(const float4*)(Wr + (size_t)(m0 + row) * DM + k0 + cb + q4 * 4);
            unsigned short* pw = usp(wT, SW128(row, (cb + q4 * 4) * 2));
            pw[0] = f2bf(wv.x); pw[1] = f2bf(wv.y); pw[2] = f2bf(wv.z); pw[3] = f2bf(wv.w);
        }
        __syncthreads();
#pragma unroll
        for (int mch = 0; mch < 4; ++mch)
#pragma unroll
            for (int kh = 0; kh < 2; ++kh) {
                short8 a  = ld8(rT, SW128(w * 16 + lr,   (kh * 32 + lg * 8) * 2));
                short8 bb = ld8(wT, SW128(mch * 16 + lr, (kh * 32 + lg * 8) * 2));
                acc[mch] = __builtin_amdgcn_mfma_f32_16x16x32_bf16(a, bb, acc[mch], 0, 0, 0);
            }
    }
#pragma unroll
    for (int mch = 0; mch < 4; ++mch)
#pragma unroll
        for (int r2 = 0; r2 < 4; ++r2) {
            const int c = c0 + w * 16 + lg * 4 + r2;
            const int d = mch * 16 + lr;
            const float val = acc[mch][r2] + br[m0 + d];
            rhb[((size_t)blockIdx.y * L + c) * DH + d] = f2bf(val);
        }
}

// ---------------------------------------------------------------------------
// K1b (fallback): f32 rh for MODE1.
// ---------------------------------------------------------------------------
__global__ __launch_bounds__(256) void rh_gemm_kernel(
    const float* __restrict__ r, const float* __restrict__ Wr,
    const float* __restrict__ br, float* __restrict__ rhf)
{
    __shared__ float As[16][65];
    __shared__ float Bs[16][65];
    const int j0 = blockIdx.x * 64;
    const int m0 = blockIdx.y * 64;
    const int tid = threadIdx.x;
    const int ty = tid >> 4, tx = tid & 15;
    float acc[4][4] = {};

    for (int k0 = 0; k0 < DM; k0 += 16) {
        const int row = tid >> 2, c4 = (tid & 3) << 2;
        float4 av = *(const float4*)(r  + (size_t)(j0 + row) * DM + k0 + c4);
        float4 bv = *(const float4*)(Wr + (size_t)(m0 + row) * DM + k0 + c4);
        __syncthreads();
        As[c4 + 0][row] = av.x; As[c4 + 1][row] = av.y;
        As[c4 + 2][row] = av.z; As[c4 + 3][row] = av.w;
        Bs[c4 + 0][row] = bv.x; Bs[c4 + 1][row] = bv.y;
        Bs[c4 + 2][row] = bv.z; Bs[c4 + 3][row] = bv.w;
        __syncthreads();
#pragma unroll
        for (int k = 0; k < 16; ++k) {
            float a[4], bb[4];
#pragma unroll
            for (int t = 0; t < 4; ++t) { a[t] = As[k][ty * 4 + t]; bb[t] = Bs[k][tx * 4 + t]; }
#pragma unroll
            for (int ii = 0; ii < 4; ++ii)
#pragma unroll
                for (int jj = 0; jj < 4; ++jj)
                    acc[ii][jj] = fmaf(a[ii], bb[jj], acc[ii][jj]);
        }
    }
#pragma unroll
    for (int ii = 0; ii < 4; ++ii) {
        const int row = j0 + ty * 4 + ii;
#pragma unroll
        for (int jj = 0; jj < 4; ++jj) {
            const int col = m0 + tx * 4 + jj;
            rhf[(size_t)row * DM + col] = acc[ii][jj] + br[col];
        }
    }
}

// ---------------------------------------------------------------------------
// Prepass: K f32[j][b][m] -> bf16 Kbf[b][n][j][d]; V -> bf16 Vtb[b][n][d][j].
// ---------------------------------------------------------------------------
__global__ __launch_bounds__(256) void prepass_kernel(
    const float* __restrict__ Kg, const float* __restrict__ Vg,
    unsigned short* __restrict__ Kbf, unsigned short* __restrict__ Vtb)
{
    __shared__ unsigned short tile[64][80];
    const int j0 = blockIdx.x * 64;
    const int b = blockIdx.y, n = blockIdx.z;
    const int bn = b * NH + n;
    const int tid = threadIdx.x;

    for (int idx = tid; idx < 64 * 16; idx += 256) {
        const int jr = idx >> 4, s4 = (idx & 15) * 4;
        const size_t src = ((size_t)(j0 + jr) * BATCH + b) * DM + n * DH + s4;
        float4 kv = *(const float4*)(Kg + src);
        ushort4 o;
        o.x = f2bf(kv.x); o.y = f2bf(kv.y); o.z = f2bf(kv.z); o.w = f2bf(kv.w);
        *(ushort4*)(Kbf + ((size_t)bn * L + j0 + jr) * DH + s4) = o;
        float4 vv4 = *(const float4*)(Vg + src);
        tile[s4 + 0][jr] = f2bf(vv4.x); tile[s4 + 1][jr] = f2bf(vv4.y);
        tile[s4 + 2][jr] = f2bf(vv4.z); tile[s4 + 3][jr] = f2bf(vv4.w);
    }
    __syncthreads();
    for (int idx = tid; idx < 64 * 8; idx += 256) {
        const int d = idx >> 3, p8 = (idx & 7) * 8;
        short8 o = *(const short8*)&tile[d][p8];
        *(short8*)(Vtb + ((size_t)bn * DH + d) * L + j0 + p8) = o;
    }
}

// ---------------------------------------------------------------------------
// wm reduce (swapped fragment layout): element (lane, r2) of
// Wf[bn][ib][gc][lane][4] is (i = ib*16 + (lane&15), j = gc*16 + (lane>>4)*4 + r2).
// ---------------------------------------------------------------------------
__global__ __launch_bounds__(256) void wm_reduce_kernel(
    const unsigned short* __restrict__ Wf, const float* __restrict__ rdeng,
    float* __restrict__ wm_out)
{
    const int i = blockIdx.x;
    const int b = blockIdx.y;
    const int ib = i >> 4, lr = i & 15;
    const int j0 = threadIdx.x * 4;
    const int gc = j0 >> 4, lg = (j0 >> 2) & 3;
    const int lane = lg * 16 + lr;
    float a0 = 0.f, a1 = 0.f, a2 = 0.f, a3 = 0.f;
#pragma unroll
    for (int n = 0; n < NH; ++n) {
        const int bn = b * NH + n;
        const float rd = rdeng[((size_t)bn << 10) + i];
        ushort4 wv = *(const ushort4*)(Wf +
            ((((size_t)bn * 64 + ib) * 64 + gc) * 64 + lane) * 4);
        a0 += bf2f(wv.x) * rd; a1 += bf2f(wv.y) * rd;
        a2 += bf2f(wv.z) * rd; a3 += bf2f(wv.w) * rd;
    }
    const size_t o = ((size_t)i * L + j0) * BATCH + b;
    wm_out[o]             = a0;
    wm_out[o + BATCH]     = a1;
    wm_out[o + 2 * BATCH] = a2;
    wm_out[o + 3 * BATCH] = a3;
}

// ---------------------------------------------------------------------------
// K2 (main): swapped-S, shifted-BD, LDS-Wt PV operand, 4 blocks/CU.
// ---------------------------------------------------------------------------
__global__ __launch_bounds__(256, 4) void attn_fused(
    const float* __restrict__ q,
    const unsigned short* __restrict__ Kbf, const unsigned short* __restrict__ Vtb,
    const unsigned char* __restrict__ maskp,
    const float* __restrict__ uu, const float* __restrict__ vvp,
    const unsigned short* __restrict__ rhb,
    float* __restrict__ out, unsigned short* __restrict__ W_ws,
    float* __restrict__ rdeng)
{
    __shared__ __align__(16) unsigned short BD[16 * BD_ST];  // 32896 B (+pv scratch)
    __shared__ __align__(16) unsigned short Wt[4][16 * WT_ST]; // 5120 B per-wave A-frag
    __shared__ unsigned char mblk[L];                        // 1024 B
    __shared__ float denomP[4][16];
    __shared__ float rdenom[16];
    __shared__ int mflags;

    // XCD-pane swizzle (verified r8: FETCH 83->21MB)
    const int lin = blockIdx.x;
    const int xcd = lin & 7, idx = lin >> 3;
    const int ib  = idx & 63;
    const int pane = xcd * 8 + (idx >> 6);
    const int b = pane >> 4, n = pane & 15;
    const int i0 = ib * 16;
    const int bn = pane;

    const int tid = threadIdx.x;
    const int w = tid >> 6, lane = tid & 63, lr = lane & 15, lg = lane >> 4;

    // ---- mask dtype detection (verified r2) + staging ----
    if (tid == 0) mflags = 0;
    __syncthreads();
    {
        int local = 0;
        for (int ww = tid; ww < 1024; ww += 256) {
            const unsigned int word = ((const unsigned int*)maskp)[ww];
            if (word == 0x3f800000u) local |= 1;
            else if (word & 0xffffff00u) local |= 2;
        }
        if (local) atomicOr(&mflags, local);
    }
    __syncthreads();
    {
        const int mtype = (mflags & 1) ? 2 : ((mflags & 2) ? 1 : 0);
        for (int j = tid; j < L; j += 256) {
            bool mv;
            if (mtype == 2)      mv = ((const float*)maskp)[j * BATCH + b] != 0.f;
            else if (mtype == 1) mv = maskp[j * BATCH + b] != 0;
            else                 mv = ((const int*)maskp)[j * BATCH + b] != 0;
            mblk[j] = mv ? 1 : 0;
        }
    }
    // zero the t==1 diagonal: BD[il][i0+il+1]
    if (tid < 16) {
        const int jz = i0 + tid + 1;
        if (jz <= 1023) BD[tid * BD_ST + jz] = 0;
    }

    // ---- Q fragments in registers (x 0.125*log2e) ----
    const float* qrow = q + ((size_t)(i0 + lr) * BATCH + b) * DM + n * DH;
    const float* urow = uu + n * DH;
    const float* vrow = vvp + n * DH;
    short8 qu_a[2], qv_a[2];
#pragma unroll
    for (int kh = 0; kh < 2; ++kh) {
        const int kb = kh * 32 + lg * 8;
        float4 qa = *(const float4*)(qrow + kb), qb = *(const float4*)(qrow + kb + 4);
        float4 ua = *(const float4*)(urow + kb), ub = *(const float4*)(urow + kb + 4);
        float4 va = *(const float4*)(vrow + kb), vb = *(const float4*)(vrow + kb + 4);
        short8 su, sv;
        su[0] = (short)f2bf((qa.x + ua.x) * CS); su[1] = (short)f2bf((qa.y + ua.y) * CS);
        su[2] = (short)f2bf((qa.z + ua.z) * CS); su[3] = (short)f2bf((qa.w + ua.w) * CS);
        su[4] = (short)f2bf((qb.x + ub.x) * CS); su[5] = (short)f2bf((qb.y + ub.y) * CS);
        su[6] = (short)f2bf((qb.z + ub.z) * CS); su[7] = (short)f2bf((qb.w + ub.w) * CS);
        sv[0] = (short)f2bf((qa.x + va.x) * CS); sv[1] = (short)f2bf((qa.y + va.y) * CS);
        sv[2] = (short)f2bf((qa.z + va.z) * CS); sv[3] = (short)f2bf((qa.w + va.w) * CS);
        sv[4] = (short)f2bf((qb.x + vb.x) * CS); sv[5] = (short)f2bf((qb.y + vb.y) * CS);
        sv[6] = (short)f2bf((qb.z + vb.z) * CS); sv[7] = (short)f2bf((qb.w + vb.w) * CS);
        qu_a[kh] = su; qv_a[kh] = sv;
    }
    float qv16[16];
    {
        const int kq = (tid & 3) * 16;
        if (i0 + 16 < L) {
            const float* q16 = q + ((size_t)(i0 + 16) * BATCH + b) * DM + n * DH;
#pragma unroll
            for (int e4 = 0; e4 < 4; ++e4) {
                float4 qa = *(const float4*)(q16 + kq + e4 * 4);
                float4 va = *(const float4*)(vrow + kq + e4 * 4);
                qv16[e4 * 4 + 0] = (qa.x + va.x) * CS; qv16[e4 * 4 + 1] = (qa.y + va.y) * CS;
                qv16[e4 * 4 + 2] = (qa.z + va.z) * CS; qv16[e4 * 4 + 3] = (qa.w + va.w) * CS;
            }
        } else {
#pragma unroll
            for (int e = 0; e < 16; ++e) qv16[e] = 0.f;
        }
    }

    // ============== BD build: shifted double-write, no internal barriers ====
    {
        const unsigned short* rpane = rhb + (size_t)n * L * DH;
        const int ccol = w * 16 + lr;
        short8 rb[2][2];
#pragma unroll
        for (int kh = 0; kh < 2; ++kh) {
            rb[0][kh] = *(const short8*)(rpane + (size_t)ccol * DH + kh * 32 + lg * 8);
            rb[1][kh] = *(const short8*)(rpane + (size_t)(64 + ccol) * DH + kh * 32 + lg * 8);
        }
        const int col16 = tid >> 2;
        const int kq = (tid & 3) * 16;
#pragma unroll
        for (int ct = 0; ct < 16; ++ct) {
            const int c0 = ct * 64;
            const int cur = ct & 1;
            short8 nk0, nk1;
            if (ct + 2 < 16) {
                nk0 = *(const short8*)(rpane + (size_t)((ct + 2) * 64 + ccol) * DH + lg * 8);
                nk1 = *(const short8*)(rpane + (size_t)((ct + 2) * 64 + ccol) * DH + 32 + lg * 8);
            }
            f32x4 acc = {0.f, 0.f, 0.f, 0.f};
#pragma unroll
            for (int kh = 0; kh < 2; ++kh)
                acc = __builtin_amdgcn_mfma_f32_16x16x32_bf16(qv_a[kh], rb[cur][kh], acc, 0, 0, 0);
            const int c = c0 + ccol;
#pragma unroll
            for (int r2 = 0; r2 < 4; ++r2) {
                const int ilp = lg * 4 + r2;
                const unsigned short hv = f2h(acc[r2]);
                const int j1 = c + i0 + ilp - 1023;          // t<=0 dest, row ilp
                if (j1 >= 0) BD[ilp * BD_ST + j1] = hv;
                const int j2 = c + i0 + ilp + 1;             // t>=2 dest, row ilp-1
                if (ilp >= 1 && j2 <= 1023) BD[(ilp - 1) * BD_ST + j2] = hv;
            }
            // row 16 (i+1 shift source for row 15): 4 threads per column
            {
                short8 ra0 = *(const short8*)(rpane + (size_t)(c0 + col16) * DH + kq);
                short8 ra1 = *(const short8*)(rpane + (size_t)(c0 + col16) * DH + kq + 8);
                float s16 = 0.f;
#pragma unroll
                for (int e = 0; e < 8; ++e) {
                    s16 = fmaf(qv16[e],     bf2f((unsigned short)ra0[e]), s16);
                    s16 = fmaf(qv16[e + 8], bf2f((unsigned short)ra1[e]), s16);
                }
                s16 += __shfl_xor(s16, 1);
                s16 += __shfl_xor(s16, 2);
                const int j16 = c0 + col16 + i0 + 17;
                if ((tid & 3) == 0 && j16 <= 1023)
                    BD[15 * BD_ST + j16] = f2h(s16);
            }
            if (ct + 2 < 16) { rb[cur][0] = nk0; rb[cur][1] = nk1; }
        }
    }
    __syncthreads();   // BD + mblk visible to all

    // ============== j-loop: zero barriers, swapped-S =======================
    const unsigned short* Kpane = Kbf + (size_t)bn * L * DH;
    const unsigned short* Vpane = Vtb + (size_t)bn * DH * L;
    const int jwbase = w * 256;
    unsigned short* WtW = &Wt[w][0];
    f32x4 pv[4] = {};
    float dl = 0.f;                       // row-lr denom partial
    const size_t wsbase = (((size_t)bn * 64 + ib) * 64) * 64 * 4;

    short8 kf[2][2];
#pragma unroll
    for (int kh = 0; kh < 2; ++kh) {
        kf[0][kh] = *(const short8*)(Kpane + (size_t)(jwbase + lr) * DH + kh * 32 + lg * 8);
        kf[1][kh] = *(const short8*)(Kpane + (size_t)(jwbase + 16 + lr) * DH + kh * 32 + lg * 8);
    }

#pragma unroll 1
    for (int sub = 0; sub < 4; ++sub) {
        const int jbase = jwbase + sub * 64;
#pragma unroll
        for (int win = 0; win < 2; ++win) {        // 32-j window
            short8 vf[4];
#pragma unroll
            for (int dch = 0; dch < 4; ++dch)
                vf[dch] = *(const short8*)(Vpane + (size_t)(dch * 16 + lr) * L
                                           + jbase + win * 32 + lg * 8);
#pragma unroll
            for (int cc = 0; cc < 2; ++cc) {
                const int chunk = sub * 4 + win * 2 + cc;
                const int cur = chunk & 1;
                short8 nk0, nk1;
                if (chunk + 2 < 16) {
                    const int jn = jwbase + (chunk + 2) * 16 + lr;
                    nk0 = *(const short8*)(Kpane + (size_t)jn * DH + lg * 8);
                    nk1 = *(const short8*)(Kpane + (size_t)jn * DH + 32 + lg * 8);
                }
                // swapped: D[j][i] -> lane holds i=lr, j = jc + lg*4 + r2
                f32x4 acc = {0.f, 0.f, 0.f, 0.f};
#pragma unroll
                for (int kh = 0; kh < 2; ++kh)
                    acc = __builtin_amdgcn_mfma_f32_16x16x32_bf16(kf[cur][kh], qu_a[kh], acc, 0, 0, 0);
                const int jc = jbase + win * 32 + cc * 16;
                const int jq = jc + lg * 4;
                const unsigned int m4 = *(const unsigned int*)&mblk[jq];
                const ushort4 bdq = *(const ushort4*)&BD[lr * BD_ST + jq];
                ushort4 wpack;
#pragma unroll
                for (int r2 = 0; r2 < 4; ++r2) {
                    const unsigned short bdh =
                        (r2 == 0) ? bdq.x : (r2 == 1) ? bdq.y : (r2 == 2) ? bdq.z : bdq.w;
                    const float mo = ((m4 >> (8 * r2)) & 0xffu) ? -1e9f : 0.f;
                    const float s = fminf(acc[r2] + h2f(bdh) + mo, 126.f);
                    const float wg = fexp2(s);
                    dl += wg;
                    ((unsigned short*)&wpack)[r2] = f2bf(wg);
                }
                // per-wave Wt (PV A-frag source): [lr][cc*16 + lg*4 .. +3]
                *(ushort4*)(WtW + lr * WT_ST + cc * 16 + lg * 4) = wpack;
                // coalesced W_ws fragment store
                *(ushort4*)(W_ws + wsbase + (((size_t)(jc >> 4)) * 64 + lane) * 4) = wpack;
                if (chunk + 2 < 16) { kf[cur][0] = nk0; kf[cur][1] = nk1; }
            }
            // ---- PV: A-frag = W[i=lr][k=lg*8..+7] from this wave's Wt ----
            short8 afrag = *(const short8*)(WtW + lr * WT_ST + lg * 8);
#pragma unroll
            for (int dch = 0; dch < 4; ++dch)
                pv[dch] = __builtin_amdgcn_mfma_f32_16x16x32_bf16(afrag, vf[dch], pv[dch], 0, 0, 0);
        }
    }

    // ---- denominators (row lr): reduce across lg groups ----
    dl += __shfl_xor(dl, 16, 64);
    dl += __shfl_xor(dl, 32, 64);
    if (lane < 16) denomP[w][lane] = dl;
    __syncthreads();                       // all BD (fp16) reads done

    // pv partials into BD region (reused as f32 scratch, per-wave private)
    {
        float* pvw = (float*)BD + w * 1024;
#pragma unroll
        for (int dch = 0; dch < 4; ++dch)
#pragma unroll
            for (int r2 = 0; r2 < 4; ++r2)
                pvw[(lg * 4 + r2) * 64 + dch * 16 + lr] = pv[dch][r2];
    }
    if (tid < 16) {
        const float dn = denomP[0][tid] + denomP[1][tid] + denomP[2][tid] + denomP[3][tid];
        rdenom[tid] = 1.f / dn;
        rdeng[((size_t)bn << 10) + i0 + tid] = 1.f / (dn * 16.f);
    }
    __syncthreads();

    // ---- out = (sum_w pv_w) * rdenom ----
    {
        const float* pvwAll = (const float*)BD;
        const int il = tid >> 4, d0 = (tid & 15) * 4;
        float4 o  = *(const float4*)(pvwAll + 0 * 1024 + il * 64 + d0);
        float4 o1 = *(const float4*)(pvwAll + 1 * 1024 + il * 64 + d0);
        float4 o2 = *(const float4*)(pvwAll + 2 * 1024 + il * 64 + d0);
        float4 o3 = *(const float4*)(pvwAll + 3 * 1024 + il * 64 + d0);
        const float rs = rdenom[il];
        o.x = (o.x + o1.x + o2.x + o3.x) * rs;
        o.y = (o.y + o1.y + o2.y + o3.y) * rs;
        o.z = (o.z + o1.z + o2.z + o3.z) * rs;
        o.w = (o.w + o1.w + o2.w + o3.w) * rs;
        *(float4*)(out + ((size_t)(i0 + il) * BATCH + b) * DM + n * DH + d0) = o;
    }
}

// ---------------------------------------------------------------------------
// Legacy K2 (round-6 structure) for fallback paths; atomic wm accumulation.
// ---------------------------------------------------------------------------
template<int MODE>
__global__ __launch_bounds__(256, 2) void attn_legacy(
    const float* __restrict__ q,
    const void* __restrict__ Kp, const void* __restrict__ Vp,
    const unsigned char* __restrict__ maskp,
    const float* __restrict__ uu, const float* __restrict__ vvp,
    const void* __restrict__ rhp,
    float* __restrict__ out, float* __restrict__ wm_out)
{
    __shared__ unsigned short QU[16 * 64];
    __shared__ unsigned short QV[17 * 64];
    __shared__ unsigned short KR[(MODE == 1) ? 64 * 64 : 8];
    __shared__ unsigned short VT[(MODE == 1) ? 64 * 64 : 8];
    __shared__ unsigned short BDp[17 * BDP_ST];
    __shared__ unsigned short Wt[2][16 * 64];
    __shared__ unsigned char mblk[L];
    __shared__ float denomP[4][16];
    __shared__ float rdenom[16];
    __shared__ int mflags;

    const int i0 = blockIdx.x * TI;
    const int b  = blockIdx.y;
    const int n  = blockIdx.z;
    const int bn = b * NH + n;
    const int tid = threadIdx.x;
    const int w = tid >> 6, lane = tid & 63, lr = lane & 15, lg = lane >> 4;

    const unsigned short* Kbf = (const unsigned short*)Kp;
    const unsigned short* Vtb = (const unsigned short*)Vp;
    const unsigned short* rhb = (const unsigned short*)rhp;
    const float* Kg  = (const float*)Kp;
    const float* Vg  = (const float*)Vp;
    const float* rhf = (const float*)rhp;

    if (tid == 0) mflags = 0;
    __syncthreads();
    {
        int local = 0;
        for (int ww = tid; ww < 1024; ww += 256) {
            const unsigned int word = ((const unsigned int*)maskp)[ww];
            if (word == 0x3f800000u) local |= 1;
            else if (word & 0xffffff00u) local |= 2;
        }
        if (local) atomicOr(&mflags, local);
    }
    __syncthreads();
    {
        const int mtype = (mflags & 1) ? 2 : ((mflags & 2) ? 1 : 0);
        for (int j = tid; j < L; j += 256) {
            bool mv;
            if (mtype == 2)      mv = ((const float*)maskp)[j * BATCH + b] != 0.f;
            else if (mtype == 1) mv = maskp[j * BATCH + b] != 0;
            else                 mv = ((const int*)maskp)[j * BATCH + b] != 0;
            mblk[j] = mv ? 1 : 0;
        }
    }
    for (int idx = tid; idx < 17 * 64; idx += 256) {
        const int row = idx >> 6, d = idx & 63;
        const int gi = i0 + row;
        const float qval = (gi < L) ? q[((size_t)gi * BATCH + b) * DM + n * DH + d] : 0.f;
        *usp(QV, SW128(row, d * 2)) = f2bf((qval + vvp[n * DH + d]) * SCALE);
        if (row < 16) *usp(QU, SW128(row, d * 2)) = f2bf((qval + uu[n * DH + d]) * SCALE);
    }
    __syncthreads();

    for (int ct = 0; ct < 16; ++ct) {
        const int c0 = ct * 64;
        const int ccol = w * 16 + lr;
        if constexpr (MODE == 1) {
            __syncthreads();
            for (int idx = tid; idx < 64 * 16; idx += 256) {
                const int cr = idx >> 4, d4 = (idx & 15) * 4;
                float4 rv = *(const float4*)(rhf + (size_t)(c0 + cr) * DM + n * DH + d4);
                unsigned short* p = usp(KR, SW128(cr, d4 * 2));
                p[0] = f2bf(rv.x); p[1] = f2bf(rv.y); p[2] = f2bf(rv.z); p[3] = f2bf(rv.w);
            }
            __syncthreads();
        }
        f32x4 acc = {0.f, 0.f, 0.f, 0.f};
#pragma unroll
        for (int kh = 0; kh < 2; ++kh) {
            short8 a = ld8(QV, SW128(lr, (kh * 32 + lg * 8) * 2));
            short8 bb;
            if constexpr (MODE == 0)
                bb = *(const short8*)(rhb + ((size_t)n * L + c0 + ccol) * DH + kh * 32 + lg * 8);
            else
                bb = ld8(KR, SW128(ccol, (kh * 32 + lg * 8) * 2));
            acc = __builtin_amdgcn_mfma_f32_16x16x32_bf16(a, bb, acc, 0, 0, 0);
        }
#pragma unroll
        for (int r2 = 0; r2 < 4; ++r2)
            BDp[(lg * 4 + r2) * BDP_ST + c0 + ccol] = f2h(acc[r2]);
        {
            const int col = tid >> 2, kq = (tid & 3) * 16;
            float s16 = 0.f;
#pragma unroll
            for (int kk = 0; kk < 16; kk += 8) {
                short8 qa = ld8(QV, SW128(16, (kq + kk) * 2));
                short8 ra;
                if constexpr (MODE == 0)
                    ra = *(const short8*)(rhb + ((size_t)n * L + c0 + col) * DH + kq + kk);
                else
                    ra = ld8(KR, SW128(col, (kq + kk) * 2));
#pragma unroll
                for (int e = 0; e < 8; ++e)
                    s16 = fmaf(bf2f((unsigned short)qa[e]), bf2f((unsigned short)ra[e]), s16);
            }
            s16 += __shfl_xor(s16, 1);
            s16 += __shfl_xor(s16, 2);
            if ((tid & 3) == 0) BDp[16 * BDP_ST + c0 + col] = f2h(s16);
        }
    }

    const int jloc = w * 16 + lr;
    __syncthreads();

    f32x4 pv = {0.f, 0.f, 0.f, 0.f};
    float dl[4] = {0.f, 0.f, 0.f, 0.f};
    float tmp[4][NJT];
#pragma unroll
    for (int jt = 0; jt < NJT; ++jt) {
        const int j0 = jt * 64;
        const int gj = j0 + jloc;
        const int cur = jt & 1;
        if constexpr (MODE == 1) {
            __syncthreads();
            for (int idx = tid; idx < 64 * 16; idx += 256) {
                const int jr = idx >> 4, d4 = (idx & 15) * 4;
                const size_t src = ((size_t)(j0 + jr) * BATCH + b) * DM + n * DH + d4;
                float4 kv = *(const float4*)(Kg + src);
                unsigned short* p = usp(KR, SW128(jr, d4 * 2));
                p[0] = f2bf(kv.x); p[1] = f2bf(kv.y); p[2] = f2bf(kv.z); p[3] = f2bf(kv.w);
                float4 vv4 = *(const float4*)(Vg + src);
                *usp(VT, SW128(d4 + 0, jr * 2)) = f2bf(vv4.x);
                *usp(VT, SW128(d4 + 1, jr * 2)) = f2bf(vv4.y);
                *usp(VT, SW128(d4 + 2, jr * 2)) = f2bf(vv4.z);
                *usp(VT, SW128(d4 + 3, jr * 2)) = f2bf(vv4.w);
            }
            __syncthreads();
        }
        f32x4 acc = {0.f, 0.f, 0.f, 0.f};
#pragma unroll
        for (int kh = 0; kh < 2; ++kh) {
            short8 a = ld8(QU, SW128(lr, (kh * 32 + lg * 8) * 2));
            short8 bb;
            if constexpr (MODE == 0)
                bb = *(const short8*)(Kbf + ((size_t)bn * L + gj) * DH + kh * 32 + lg * 8);
            else
                bb = ld8(KR, SW128(jloc, (kh * 32 + lg * 8) * 2));
            acc = __builtin_amdgcn_mfma_f32_16x16x32_bf16(a, bb, acc, 0, 0, 0);
        }
        const bool msk = mblk[gj] != 0;
#pragma unroll
        for (int r2 = 0; r2 < 4; ++r2) {
            const int il = lg * 4 + r2;
            const int gi = i0 + il;
            const int t = gj - gi;
            float bd = 0.f;
            if (t != 1) {
                const int c = (t <= 0) ? (L - 1 + t) : (t - 2);
                bd = h2f(BDp[(il + (t >= 1 ? 1 : 0)) * BDP_ST + c]);
            }
            float s = acc[r2] + bd;
            if (msk) s = -1e9f;
            const float wgt = __expf(fminf(s, 80.f));
            dl[r2] += wgt;
            tmp[r2][jt] = wgt;
            *usp(Wt[cur], SW128(il, jloc * 2)) = f2bf(wgt);
        }
        __syncthreads();
#pragma unroll
        for (int kh = 0; kh < 2; ++kh) {
            short8 a = ld8(Wt[cur], SW128(lr, (kh * 32 + lg * 8) * 2));
            short8 bb;
            if constexpr (MODE == 0)
                bb = *(const short8*)(Vtb + ((size_t)bn * DH + jloc) * L + j0 + kh * 32 + lg * 8);
            else
                bb = ld8(VT, SW128(jloc, (kh * 32 + lg * 8) * 2));
            pv = __builtin_amdgcn_mfma_f32_16x16x32_bf16(a, bb, pv, 0, 0, 0);
        }
    }

#pragma unroll
    for (int r2 = 0; r2 < 4; ++r2) {
        float d = dl[r2];
        d += __shfl_xor(d, 1); d += __shfl_xor(d, 2);
        d += __shfl_xor(d, 4); d += __shfl_xor(d, 8);
        if (lr == 0) denomP[w][lg * 4 + r2] = d;
    }
    __syncthreads();
    if (tid < 16)
        rdenom[tid] = 1.f / (denomP[0][tid] + denomP[1][tid] + denomP[2][tid] + denomP[3][tid]);
    __syncthreads();

#pragma unroll
    for (int r2 = 0; r2 < 4; ++r2) {
        const int il = lg * 4 + r2;
        out[((size_t)(i0 + il) * BATCH + b) * DM + n * DH + w * 16 + lr] = pv[r2] * rdenom[il];
    }
#pragma unroll
    for (int r2 = 0; r2 < 4; ++r2) {
        const int il = lg * 4 + r2;
        const float rs = rdenom[il] * (1.f / 16.f);
#pragma unroll
        for (int jt = 0; jt < NJT; ++jt)
            atomicAdd(wm_out + ((size_t)(i0 + il) * L + jt * 64 + jloc) * BATCH + b,
                      tmp[r2][jt] * rs);
    }
}

// ---------------------------------------------------------------------------
extern "C" void kernel_launch(void* const* d_in, const int* in_sizes, int n_in,
                              void* d_out, int out_size, void* d_ws, size_t ws_size,
                              hipStream_t stream)
{
    (void)in_sizes; (void)n_in; (void)out_size;
    const float* q   = (const float*)d_in[0];
    const float* K   = (const float*)d_in[1];
    const float* V   = (const float*)d_in[2];
    const unsigned char* mask = (const unsigned char*)d_in[3];
    const float* r   = (const float*)d_in[4];
    const float* u   = (const float*)d_in[5];
    const float* v   = (const float*)d_in[6];
    const float* Wr  = (const float*)d_in[7];
    const float* br  = (const float*)d_in[8];

    float* out = (float*)d_out;                    // (1024, 4, 1024)
    float* wm  = out + (size_t)L * BATCH * DM;     // (1024, 1024, 4)

    const size_t kvbytes = (size_t)BATCH * NH * L * DH * 2;   // 8 MB each
    const size_t rhbytes = (size_t)NH * L * DH * 2;           // 2 MB
    const size_t wmbytes = (size_t)BATCH * NH * L * L * 2;    // 134 MB
    const size_t rdbytes = (size_t)BATCH * NH * L * 4;        // 256 KB

    if (ws_size >= 2 * kvbytes + rhbytes + wmbytes + rdbytes) {
        unsigned short* Kbf = (unsigned short*)d_ws;
        unsigned short* Vtb = Kbf + kvbytes / 2;
        unsigned short* rhb = Vtb + kvbytes / 2;
        unsigned short* Wws = rhb + rhbytes / 2;
        float* rdeng = (float*)(Wws + wmbytes / 2);
        rh_gemm_mfma<<<dim3(16, 16), 256, 0, stream>>>(r, Wr, br, rhb);
        prepass_kernel<<<dim3(16, 4, 16), 256, 0, stream>>>(K, V, Kbf, Vtb);
        attn_fused<<<dim3(4096), 256, 0, stream>>>(
            q, Kbf, Vtb, mask, u, v, rhb, out, Wws, rdeng);
        wm_reduce_kernel<<<dim3(L, BATCH), 256, 0, stream>>>(Wws, rdeng, wm);
    } else if (ws_size >= 2 * kvbytes + rhbytes) {
        hipMemsetAsync(wm, 0, (size_t)L * L * BATCH * sizeof(float), stream);
        unsigned short* Kbf = (unsigned short*)d_ws;
        unsigned short* Vtb = Kbf + kvbytes / 2;
        unsigned short* rhb = Vtb + kvbytes / 2;
        rh_gemm_mfma<<<dim3(16, 16), 256, 0, stream>>>(r, Wr, br, rhb);
        prepass_kernel<<<dim3(16, 4, 16), 256, 0, stream>>>(K, V, Kbf, Vtb);
        attn_legacy<0><<<dim3(64, 4, 16), 256, 0, stream>>>(
            q, Kbf, Vtb, mask, u, v, rhb, out, wm);
    } else {
        hipMemsetAsync(wm, 0, (size_t)L * L * BATCH * sizeof(float), stream);
        float* rhf = (float*)d_ws;
        rh_gemm_kernel<<<dim3(16, 16), 256, 0, stream>>>(r, Wr, br, rhf);
        attn_legacy<1><<<dim3(64, 4, 16), 256, 0, stream>>>(
            q, K, V, mask, u, v, rhf, out, wm);
    }
}

// Round 11
// 290.869 us; speedup vs baseline: 1.4502x; 1.4502x over previous
//
#include <hip/hip_runtime.h>
#include <hip/hip_fp16.h>
#include <stdint.h>

// Transformer-XL relative attention, round 11: read-coalesced wm_reduce
// (fixes r10's 135us aux regression) + fully-unrolled attn j-loop.
// L=qlen=klen=1024, BATCH=4, NH=16, DH=64, DM=1024.
//
// Main-path structure (verified r10): one head-i-tile per block, 4 waves,
// wave owns j-range [w*256,(w+1)*256):
//  - S^T via mfma(K, Q): lane (lg,lr) holds S for i=lr, j = chunk*16+lg*4+r2.
//    BD gather = ONE ds_read_b64; mask = one u32.
//  - BD stored ALREADY REL-SHIFTED: BDp[i'][c] -> BD[i'][c+i0+i'-1023] (t<=0),
//    BD[i'-1][c+i0+i'+1] (t>=2); row16 VALU -> BD[15][c+i0+17]; diagonal
//    BD[i][i0+i+1] pre-zeroed (t==1).
//  - PV A-frag via per-wave LDS Wt round-trip (in-wave ordering only).
//  - XCD-pane swizzle (r8: FETCH 83->21MB), depth-2 K/rh prefetch.
//  - LDS ~39.4KB, __launch_bounds__(256,4): 4 blocks/CU.
// W_ws fragment layout: element (lane,r2) of Wf[bn][ib][gc][lane][4] is
// (i = ib*16 + (lane&15), j = gc*16 + (lane>>4)*4 + r2); one wave's 512B
// line = one full 16x16 (i,j) tile -> coalesced reduce.

#define L 1024
#define BATCH 4
#define NH 16
#define DH 64
#define DM 1024
#define TI 16
#define NJT 16
#define BD_ST 1028
#define BDP_ST 1032
#define WT_ST 40
#define SCALE 0.125f
#define CS 0.18033688011112042f   // 0.125 * log2(e)

typedef __attribute__((ext_vector_type(8))) short short8;
typedef __attribute__((ext_vector_type(4))) float f32x4;

static __device__ __forceinline__ unsigned short f2bf(float f) {
    union { float f; unsigned int u; } x; x.f = f;
    return (unsigned short)((x.u + 0x7fffu + ((x.u >> 16) & 1u)) >> 16);  // RNE
}
static __device__ __forceinline__ float bf2f(unsigned short h) {
    union { unsigned int u; float f; } x; x.u = ((unsigned int)h) << 16;
    return x.f;
}
static __device__ __forceinline__ unsigned short f2h(float f) {
    __half h = __float2half(f);
    union { __half h; unsigned short s; } x; x.h = h; return x.s;
}
static __device__ __forceinline__ float h2f(unsigned short s) {
    union { __half h; unsigned short s; } x; x.s = s; return __half2float(x.h);
}
static __device__ __forceinline__ unsigned short* usp(void* base, int byteoff) {
    return (unsigned short*)((char*)base + byteoff);
}
static __device__ __forceinline__ short8 ld8(const void* base, int byteoff) {
    return *(const short8*)((const char*)base + byteoff);
}
static __device__ __forceinline__ float fexp2(float x) {
#if __has_builtin(__builtin_amdgcn_exp2f)
    return __builtin_amdgcn_exp2f(x);
#else
    return __expf(x * 0.6931471805599453f);
#endif
}
#define SW128(row, colByte) ((((row) * 128) + (colByte)) ^ (((row) & 7) << 4))

// ---------------------------------------------------------------------------
// K1a (main): rh = r @ Wr^T + br via bf16 MFMA -> rhb [n][c][d] bf16.
// ---------------------------------------------------------------------------
__global__ __launch_bounds__(256) void rh_gemm_mfma(
    const float* __restrict__ r, const float* __restrict__ Wr,
    const float* __restrict__ br, unsigned short* __restrict__ rhb)
{
    __shared__ unsigned short rT[64 * 64];
    __shared__ unsigned short wT[64 * 64];
    const int c0 = blockIdx.x * 64, m0 = blockIdx.y * 64;
    const int tid = threadIdx.x;
    const int w = tid >> 6, lane = tid & 63, lr = lane & 15, lg = lane >> 4;
    f32x4 acc[4] = {};

    for (int kt = 0; kt < 16; ++kt) {
        const int k0 = kt * 64;
        __syncthreads();
        const int row = tid >> 2, cb = (tid & 3) * 16;
#pragma unroll
        for (int q4 = 0; q4 < 4; ++q4) {
            float4 rv = *(const float4*)(r + (size_t)(c0 + row) * DM + k0 + cb + q4 * 4);
            unsigned short* p = usp(rT, SW128(row, (cb + q4 * 4) * 2));
            p[0] = f2bf(rv.x); p[1] = f2bf(rv.y); p[2] = f2bf(rv.z); p[3] = f2bf(rv.w);
            float4 wv = *(const float4*)(Wr + (size_t)(m0 + row) * DM + k0 + cb + q4 * 4);
            unsigned short* pw = usp(wT, SW128(row, (cb + q4 * 4) * 2));
            pw[0] = f2bf(wv.x); pw[1] = f2bf(wv.y); pw[2] = f2bf(wv.z); pw[3] = f2bf(wv.w);
        }
        __syncthreads();
#pragma unroll
        for (int mch = 0; mch < 4; ++mch)
#pragma unroll
            for (int kh = 0; kh < 2; ++kh) {
                short8 a  = ld8(rT, SW128(w * 16 + lr,   (kh * 32 + lg * 8) * 2));
                short8 bb = ld8(wT, SW128(mch * 16 + lr, (kh * 32 + lg * 8) * 2));
                acc[mch] = __builtin_amdgcn_mfma_f32_16x16x32_bf16(a, bb, acc[mch], 0, 0, 0);
            }
    }
#pragma unroll
    for (int mch = 0; mch < 4; ++mch)
#pragma unroll
        for (int r2 = 0; r2 < 4; ++r2) {
            const int c = c0 + w * 16 + lg * 4 + r2;
            const int d = mch * 16 + lr;
            const float val = acc[mch][r2] + br[m0 + d];
            rhb[((size_t)blockIdx.y * L + c) * DH + d] = f2bf(val);
        }
}

// ---------------------------------------------------------------------------
// K1b (fallback): f32 rh for MODE1.
// ---------------------------------------------------------------------------
__global__ __launch_bounds__(256) void rh_gemm_kernel(
    const float* __restrict__ r, const float* __restrict__ Wr,
    const float* __restrict__ br, float* __restrict__ rhf)
{
    __shared__ float As[16][65];
    __shared__ float Bs[16][65];
    const int j0 = blockIdx.x * 64;
    const int m0 = blockIdx.y * 64;
    const int tid = threadIdx.x;
    const int ty = tid >> 4, tx = tid & 15;
    float acc[4][4] = {};

    for (int k0 = 0; k0 < DM; k0 += 16) {
        const int row = tid >> 2, c4 = (tid & 3) << 2;
        float4 av = *(const float4*)(r  + (size_t)(j0 + row) * DM + k0 + c4);
        float4 bv = *(const float4*)(Wr + (size_t)(m0 + row) * DM + k0 + c4);
        __syncthreads();
        As[c4 + 0][row] = av.x; As[c4 + 1][row] = av.y;
        As[c4 + 2][row] = av.z; As[c4 + 3][row] = av.w;
        Bs[c4 + 0][row] = bv.x; Bs[c4 + 1][row] = bv.y;
        Bs[c4 + 2][row] = bv.z; Bs[c4 + 3][row] = bv.w;
        __syncthreads();
#pragma unroll
        for (int k = 0; k < 16; ++k) {
            float a[4], bb[4];
#pragma unroll
            for (int t = 0; t < 4; ++t) { a[t] = As[k][ty * 4 + t]; bb[t] = Bs[k][tx * 4 + t]; }
#pragma unroll
            for (int ii = 0; ii < 4; ++ii)
#pragma unroll
                for (int jj = 0; jj < 4; ++jj)
                    acc[ii][jj] = fmaf(a[ii], bb[jj], acc[ii][jj]);
        }
    }
#pragma unroll
    for (int ii = 0; ii < 4; ++ii) {
        const int row = j0 + ty * 4 + ii;
#pragma unroll
        for (int jj = 0; jj < 4; ++jj) {
            const int col = m0 + tx * 4 + jj;
            rhf[(size_t)row * DM + col] = acc[ii][jj] + br[col];
        }
    }
}

// ---------------------------------------------------------------------------
// Prepass: K f32[j][b][m] -> bf16 Kbf[b][n][j][d]; V -> bf16 Vtb[b][n][d][j].
// ---------------------------------------------------------------------------
__global__ __launch_bounds__(256) void prepass_kernel(
    const float* __restrict__ Kg, const float* __restrict__ Vg,
    unsigned short* __restrict__ Kbf, unsigned short* __restrict__ Vtb)
{
    __shared__ unsigned short tile[64][80];
    const int j0 = blockIdx.x * 64;
    const int b = blockIdx.y, n = blockIdx.z;
    const int bn = b * NH + n;
    const int tid = threadIdx.x;

    for (int idx = tid; idx < 64 * 16; idx += 256) {
        const int jr = idx >> 4, s4 = (idx & 15) * 4;
        const size_t src = ((size_t)(j0 + jr) * BATCH + b) * DM + n * DH + s4;
        float4 kv = *(const float4*)(Kg + src);
        ushort4 o;
        o.x = f2bf(kv.x); o.y = f2bf(kv.y); o.z = f2bf(kv.z); o.w = f2bf(kv.w);
        *(ushort4*)(Kbf + ((size_t)bn * L + j0 + jr) * DH + s4) = o;
        float4 vv4 = *(const float4*)(Vg + src);
        tile[s4 + 0][jr] = f2bf(vv4.x); tile[s4 + 1][jr] = f2bf(vv4.y);
        tile[s4 + 2][jr] = f2bf(vv4.z); tile[s4 + 3][jr] = f2bf(vv4.w);
    }
    __syncthreads();
    for (int idx = tid; idx < 64 * 8; idx += 256) {
        const int d = idx >> 3, p8 = (idx & 7) * 8;
        short8 o = *(const short8*)&tile[d][p8];
        *(short8*)(Vtb + ((size_t)bn * DH + d) * L + j0 + p8) = o;
    }
}

// ---------------------------------------------------------------------------
// wm reduce, READ-COALESCED: grid (ib=64, gcq=4, b=4), 256 thr (4 waves).
// Wave w handles gc = gcq*16 + w*4 + k (k=0..3). One (gc,n) read per wave is
// 64 consecutive ushort4 = 512B contiguous. rdeng preloaded per thread.
// Element (lane,r2): i = ib*16+lr, j = gc*16+lg*4+r2;
// wm_out[(i*L+j)*BATCH+b] = sum_n Wf * rdeng[bn][i].
// ---------------------------------------------------------------------------
__global__ __launch_bounds__(256) void wm_reduce_kernel(
    const unsigned short* __restrict__ Wf, const float* __restrict__ rdeng,
    float* __restrict__ wm_out)
{
    const int ib = blockIdx.x;
    const int gq = blockIdx.y;
    const int b  = blockIdx.z;
    const int tid = threadIdx.x;
    const int w = tid >> 6, lane = tid & 63, lr = lane & 15, lg = lane >> 4;
    const int i = ib * 16 + lr;

    float rd[NH];
#pragma unroll
    for (int n = 0; n < NH; ++n)
        rd[n] = rdeng[((size_t)(b * NH + n) << 10) + i];

#pragma unroll
    for (int k = 0; k < 4; ++k) {
        const int gc = gq * 16 + w * 4 + k;
        float a0 = 0.f, a1 = 0.f, a2 = 0.f, a3 = 0.f;
#pragma unroll
        for (int n = 0; n < NH; ++n) {
            const int bn = b * NH + n;
            ushort4 wv = *(const ushort4*)(Wf +
                (((size_t)(bn * 64 + ib) * 64 + gc) * 64 + lane) * 4);
            a0 += bf2f(wv.x) * rd[n]; a1 += bf2f(wv.y) * rd[n];
            a2 += bf2f(wv.z) * rd[n]; a3 += bf2f(wv.w) * rd[n];
        }
        const size_t o = ((size_t)i * L + gc * 16 + lg * 4) * BATCH + b;
        wm_out[o]             = a0;
        wm_out[o + BATCH]     = a1;
        wm_out[o + 2 * BATCH] = a2;
        wm_out[o + 3 * BATCH] = a3;
    }
}

// ---------------------------------------------------------------------------
// K2 (main): swapped-S, shifted-BD, LDS-Wt PV operand, 4 blocks/CU.
// ---------------------------------------------------------------------------
__global__ __launch_bounds__(256, 4) void attn_fused(
    const float* __restrict__ q,
    const unsigned short* __restrict__ Kbf, const unsigned short* __restrict__ Vtb,
    const unsigned char* __restrict__ maskp,
    const float* __restrict__ uu, const float* __restrict__ vvp,
    const unsigned short* __restrict__ rhb,
    float* __restrict__ out, unsigned short* __restrict__ W_ws,
    float* __restrict__ rdeng)
{
    __shared__ __align__(16) unsigned short BD[16 * BD_ST];    // 32896 B (+pv scratch)
    __shared__ __align__(16) unsigned short Wt[4][16 * WT_ST]; // 5120 B per-wave A-frag
    __shared__ unsigned char mblk[L];
    __shared__ float denomP[4][16];
    __shared__ float rdenom[16];
    __shared__ int mflags;

    // XCD-pane swizzle (verified r8: FETCH 83->21MB)
    const int lin = blockIdx.x;
    const int xcd = lin & 7, idx = lin >> 3;
    const int ib  = idx & 63;
    const int pane = xcd * 8 + (idx >> 6);
    const int b = pane >> 4, n = pane & 15;
    const int i0 = ib * 16;
    const int bn = pane;

    const int tid = threadIdx.x;
    const int w = tid >> 6, lane = tid & 63, lr = lane & 15, lg = lane >> 4;

    // ---- mask dtype detection (verified r2) + staging ----
    if (tid == 0) mflags = 0;
    __syncthreads();
    {
        int local = 0;
        for (int ww = tid; ww < 1024; ww += 256) {
            const unsigned int word = ((const unsigned int*)maskp)[ww];
            if (word == 0x3f800000u) local |= 1;
            else if (word & 0xffffff00u) local |= 2;
        }
        if (local) atomicOr(&mflags, local);
    }
    __syncthreads();
    {
        const int mtype = (mflags & 1) ? 2 : ((mflags & 2) ? 1 : 0);
        for (int j = tid; j < L; j += 256) {
            bool mv;
            if (mtype == 2)      mv = ((const float*)maskp)[j * BATCH + b] != 0.f;
            else if (mtype == 1) mv = maskp[j * BATCH + b] != 0;
            else                 mv = ((const int*)maskp)[j * BATCH + b] != 0;
            mblk[j] = mv ? 1 : 0;
        }
    }
    // zero the t==1 diagonal: BD[il][i0+il+1]
    if (tid < 16) {
        const int jz = i0 + tid + 1;
        if (jz <= 1023) BD[tid * BD_ST + jz] = 0;
    }

    // ---- Q fragments in registers (x 0.125*log2e) ----
    const float* qrow = q + ((size_t)(i0 + lr) * BATCH + b) * DM + n * DH;
    const float* urow = uu + n * DH;
    const float* vrow = vvp + n * DH;
    short8 qu_a[2], qv_a[2];
#pragma unroll
    for (int kh = 0; kh < 2; ++kh) {
        const int kb = kh * 32 + lg * 8;
        float4 qa = *(const float4*)(qrow + kb), qb = *(const float4*)(qrow + kb + 4);
        float4 ua = *(const float4*)(urow + kb), ub = *(const float4*)(urow + kb + 4);
        float4 va = *(const float4*)(vrow + kb), vb = *(const float4*)(vrow + kb + 4);
        short8 su, sv;
        su[0] = (short)f2bf((qa.x + ua.x) * CS); su[1] = (short)f2bf((qa.y + ua.y) * CS);
        su[2] = (short)f2bf((qa.z + ua.z) * CS); su[3] = (short)f2bf((qa.w + ua.w) * CS);
        su[4] = (short)f2bf((qb.x + ub.x) * CS); su[5] = (short)f2bf((qb.y + ub.y) * CS);
        su[6] = (short)f2bf((qb.z + ub.z) * CS); su[7] = (short)f2bf((qb.w + ub.w) * CS);
        sv[0] = (short)f2bf((qa.x + va.x) * CS); sv[1] = (short)f2bf((qa.y + va.y) * CS);
        sv[2] = (short)f2bf((qa.z + va.z) * CS); sv[3] = (short)f2bf((qa.w + va.w) * CS);
        sv[4] = (short)f2bf((qb.x + vb.x) * CS); sv[5] = (short)f2bf((qb.y + vb.y) * CS);
        sv[6] = (short)f2bf((qb.z + vb.z) * CS); sv[7] = (short)f2bf((qb.w + vb.w) * CS);
        qu_a[kh] = su; qv_a[kh] = sv;
    }
    float qv16[16];
    {
        const int kq = (tid & 3) * 16;
        if (i0 + 16 < L) {
            const float* q16 = q + ((size_t)(i0 + 16) * BATCH + b) * DM + n * DH;
#pragma unroll
            for (int e4 = 0; e4 < 4; ++e4) {
                float4 qa = *(const float4*)(q16 + kq + e4 * 4);
                float4 va = *(const float4*)(vrow + kq + e4 * 4);
                qv16[e4 * 4 + 0] = (qa.x + va.x) * CS; qv16[e4 * 4 + 1] = (qa.y + va.y) * CS;
                qv16[e4 * 4 + 2] = (qa.z + va.z) * CS; qv16[e4 * 4 + 3] = (qa.w + va.w) * CS;
            }
        } else {
#pragma unroll
            for (int e = 0; e < 16; ++e) qv16[e] = 0.f;
        }
    }

    // ============== BD build: shifted double-write, no internal barriers ====
    {
        const unsigned short* rpane = rhb + (size_t)n * L * DH;
        const int ccol = w * 16 + lr;
        short8 rb[2][2];
#pragma unroll
        for (int kh = 0; kh < 2; ++kh) {
            rb[0][kh] = *(const short8*)(rpane + (size_t)ccol * DH + kh * 32 + lg * 8);
            rb[1][kh] = *(const short8*)(rpane + (size_t)(64 + ccol) * DH + kh * 32 + lg * 8);
        }
        const int col16 = tid >> 2;
        const int kq = (tid & 3) * 16;
#pragma unroll
        for (int ct = 0; ct < 16; ++ct) {
            const int c0 = ct * 64;
            const int cur = ct & 1;
            short8 nk0, nk1;
            if (ct + 2 < 16) {
                nk0 = *(const short8*)(rpane + (size_t)((ct + 2) * 64 + ccol) * DH + lg * 8);
                nk1 = *(const short8*)(rpane + (size_t)((ct + 2) * 64 + ccol) * DH + 32 + lg * 8);
            }
            f32x4 acc = {0.f, 0.f, 0.f, 0.f};
#pragma unroll
            for (int kh = 0; kh < 2; ++kh)
                acc = __builtin_amdgcn_mfma_f32_16x16x32_bf16(qv_a[kh], rb[cur][kh], acc, 0, 0, 0);
            const int c = c0 + ccol;
#pragma unroll
            for (int r2 = 0; r2 < 4; ++r2) {
                const int ilp = lg * 4 + r2;
                const unsigned short hv = f2h(acc[r2]);
                const int j1 = c + i0 + ilp - 1023;          // t<=0 dest, row ilp
                if (j1 >= 0) BD[ilp * BD_ST + j1] = hv;
                const int j2 = c + i0 + ilp + 1;             // t>=2 dest, row ilp-1
                if (ilp >= 1 && j2 <= 1023) BD[(ilp - 1) * BD_ST + j2] = hv;
            }
            // row 16 (i+1 shift source for row 15): 4 threads per column
            {
                short8 ra0 = *(const short8*)(rpane + (size_t)(c0 + col16) * DH + kq);
                short8 ra1 = *(const short8*)(rpane + (size_t)(c0 + col16) * DH + kq + 8);
                float s16 = 0.f;
#pragma unroll
                for (int e = 0; e < 8; ++e) {
                    s16 = fmaf(qv16[e],     bf2f((unsigned short)ra0[e]), s16);
                    s16 = fmaf(qv16[e + 8], bf2f((unsigned short)ra1[e]), s16);
                }
                s16 += __shfl_xor(s16, 1);
                s16 += __shfl_xor(s16, 2);
                const int j16 = c0 + col16 + i0 + 17;
                if ((tid & 3) == 0 && j16 <= 1023)
                    BD[15 * BD_ST + j16] = f2h(s16);
            }
            if (ct + 2 < 16) { rb[cur][0] = nk0; rb[cur][1] = nk1; }
        }
    }
    __syncthreads();   // BD + mblk visible to all

    // ============== j-loop: zero barriers, swapped-S =======================
    const unsigned short* Kpane = Kbf + (size_t)bn * L * DH;
    const unsigned short* Vpane = Vtb + (size_t)bn * DH * L;
    const int jwbase = w * 256;
    unsigned short* WtW = &Wt[w][0];
    f32x4 pv[4] = {};
    float dl = 0.f;
    const size_t wsbase = (((size_t)bn * 64 + ib) * 64) * 64 * 4;

    short8 kf[2][2];
#pragma unroll
    for (int kh = 0; kh < 2; ++kh) {
        kf[0][kh] = *(const short8*)(Kpane + (size_t)(jwbase + lr) * DH + kh * 32 + lg * 8);
        kf[1][kh] = *(const short8*)(Kpane + (size_t)(jwbase + 16 + lr) * DH + kh * 32 + lg * 8);
    }

#pragma unroll
    for (int sub = 0; sub < 4; ++sub) {
        const int jbase = jwbase + sub * 64;
#pragma unroll
        for (int win = 0; win < 2; ++win) {        // 32-j window
            short8 vf[4];
#pragma unroll
            for (int dch = 0; dch < 4; ++dch)
                vf[dch] = *(const short8*)(Vpane + (size_t)(dch * 16 + lr) * L
                                           + jbase + win * 32 + lg * 8);
#pragma unroll
            for (int cc = 0; cc < 2; ++cc) {
                const int chunk = sub * 4 + win * 2 + cc;
                const int cur = chunk & 1;
                short8 nk0, nk1;
                if (chunk + 2 < 16) {
                    const int jn = jwbase + (chunk + 2) * 16 + lr;
                    nk0 = *(const short8*)(Kpane + (size_t)jn * DH + lg * 8);
                    nk1 = *(const short8*)(Kpane + (size_t)jn * DH + 32 + lg * 8);
                }
                // swapped: D[j][i] -> lane holds i=lr, j = jc + lg*4 + r2
                f32x4 acc = {0.f, 0.f, 0.f, 0.f};
#pragma unroll
                for (int kh = 0; kh < 2; ++kh)
                    acc = __builtin_amdgcn_mfma_f32_16x16x32_bf16(kf[cur][kh], qu_a[kh], acc, 0, 0, 0);
                const int jc = jbase + win * 32 + cc * 16;
                const int jq = jc + lg * 4;
                const unsigned int m4 = *(const unsigned int*)&mblk[jq];
                const ushort4 bdq = *(const ushort4*)&BD[lr * BD_ST + jq];
                ushort4 wpack;
#pragma unroll
                for (int r2 = 0; r2 < 4; ++r2) {
                    const unsigned short bdh =
                        (r2 == 0) ? bdq.x : (r2 == 1) ? bdq.y : (r2 == 2) ? bdq.z : bdq.w;
                    const float mo = ((m4 >> (8 * r2)) & 0xffu) ? -1e9f : 0.f;
                    const float s = fminf(acc[r2] + h2f(bdh) + mo, 126.f);
                    const float wg = fexp2(s);
                    dl += wg;
                    ((unsigned short*)&wpack)[r2] = f2bf(wg);
                }
                *(ushort4*)(WtW + lr * WT_ST + cc * 16 + lg * 4) = wpack;
                *(ushort4*)(W_ws + wsbase + (((size_t)(jc >> 4)) * 64 + lane) * 4) = wpack;
                if (chunk + 2 < 16) { kf[cur][0] = nk0; kf[cur][1] = nk1; }
            }
            // ---- PV: A-frag = W[i=lr][k=lg*8..+7] from this wave's Wt ----
            short8 afrag = *(const short8*)(WtW + lr * WT_ST + lg * 8);
#pragma unroll
            for (int dch = 0; dch < 4; ++dch)
                pv[dch] = __builtin_amdgcn_mfma_f32_16x16x32_bf16(afrag, vf[dch], pv[dch], 0, 0, 0);
        }
    }

    // ---- denominators (row lr): reduce across lg groups ----
    dl += __shfl_xor(dl, 16, 64);
    dl += __shfl_xor(dl, 32, 64);
    if (lane < 16) denomP[w][lane] = dl;
    __syncthreads();                       // all BD (fp16) reads done

    // pv partials into BD region (reused as f32 scratch, per-wave private)
    {
        float* pvw = (float*)BD + w * 1024;
#pragma unroll
        for (int dch = 0; dch < 4; ++dch)
#pragma unroll
            for (int r2 = 0; r2 < 4; ++r2)
                pvw[(lg * 4 + r2) * 64 + dch * 16 + lr] = pv[dch][r2];
    }
    if (tid < 16) {
        const float dn = denomP[0][tid] + denomP[1][tid] + denomP[2][tid] + denomP[3][tid];
        rdenom[tid] = 1.f / dn;
        rdeng[((size_t)bn << 10) + i0 + tid] = 1.f / (dn * 16.f);
    }
    __syncthreads();

    // ---- out = (sum_w pv_w) * rdenom ----
    {
        const float* pvwAll = (const float*)BD;
        const int il = tid >> 4, d0 = (tid & 15) * 4;
        float4 o  = *(const float4*)(pvwAll + 0 * 1024 + il * 64 + d0);
        float4 o1 = *(const float4*)(pvwAll + 1 * 1024 + il * 64 + d0);
        float4 o2 = *(const float4*)(pvwAll + 2 * 1024 + il * 64 + d0);
        float4 o3 = *(const float4*)(pvwAll + 3 * 1024 + il * 64 + d0);
        const float rs = rdenom[il];
        o.x = (o.x + o1.x + o2.x + o3.x) * rs;
        o.y = (o.y + o1.y + o2.y + o3.y) * rs;
        o.z = (o.z + o1.z + o2.z + o3.z) * rs;
        o.w = (o.w + o1.w + o2.w + o3.w) * rs;
        *(float4*)(out + ((size_t)(i0 + il) * BATCH + b) * DM + n * DH + d0) = o;
    }
}

// ---------------------------------------------------------------------------
// Legacy K2 (round-6 structure) for fallback paths; atomic wm accumulation.
// ---------------------------------------------------------------------------
template<int MODE>
__global__ __launch_bounds__(256, 2) void attn_legacy(
    const float* __restrict__ q,
    const void* __restrict__ Kp, const void* __restrict__ Vp,
    const unsigned char* __restrict__ maskp,
    const float* __restrict__ uu, const float* __restrict__ vvp,
    const void* __restrict__ rhp,
    float* __restrict__ out, float* __restrict__ wm_out)
{
    __shared__ unsigned short QU[16 * 64];
    __shared__ unsigned short QV[17 * 64];
    __shared__ unsigned short KR[(MODE == 1) ? 64 * 64 : 8];
    __shared__ unsigned short VT[(MODE == 1) ? 64 * 64 : 8];
    __shared__ unsigned short BDp[17 * BDP_ST];
    __shared__ unsigned short Wt[2][16 * 64];
    __shared__ unsigned char mblk[L];
    __shared__ float denomP[4][16];
    __shared__ float rdenom[16];
    __shared__ int mflags;

    const int i0 = blockIdx.x * TI;
    const int b  = blockIdx.y;
    const int n  = blockIdx.z;
    const int bn = b * NH + n;
    const int tid = threadIdx.x;
    const int w = tid >> 6, lane = tid & 63, lr = lane & 15, lg = lane >> 4;

    const unsigned short* Kbf = (const unsigned short*)Kp;
    const unsigned short* Vtb = (const unsigned short*)Vp;
    const unsigned short* rhb = (const unsigned short*)rhp;
    const float* Kg  = (const float*)Kp;
    const float* Vg  = (const float*)Vp;
    const float* rhf = (const float*)rhp;

    if (tid == 0) mflags = 0;
    __syncthreads();
    {
        int local = 0;
        for (int ww = tid; ww < 1024; ww += 256) {
            const unsigned int word = ((const unsigned int*)maskp)[ww];
            if (word == 0x3f800000u) local |= 1;
            else if (word & 0xffffff00u) local |= 2;
        }
        if (local) atomicOr(&mflags, local);
    }
    __syncthreads();
    {
        const int mtype = (mflags & 1) ? 2 : ((mflags & 2) ? 1 : 0);
        for (int j = tid; j < L; j += 256) {
            bool mv;
            if (mtype == 2)      mv = ((const float*)maskp)[j * BATCH + b] != 0.f;
            else if (mtype == 1) mv = maskp[j * BATCH + b] != 0;
            else                 mv = ((const int*)maskp)[j * BATCH + b] != 0;
            mblk[j] = mv ? 1 : 0;
        }
    }
    for (int idx = tid; idx < 17 * 64; idx += 256) {
        const int row = idx >> 6, d = idx & 63;
        const int gi = i0 + row;
        const float qval = (gi < L) ? q[((size_t)gi * BATCH + b) * DM + n * DH + d] : 0.f;
        *usp(QV, SW128(row, d * 2)) = f2bf((qval + vvp[n * DH + d]) * SCALE);
        if (row < 16) *usp(QU, SW128(row, d * 2)) = f2bf((qval + uu[n * DH + d]) * SCALE);
    }
    __syncthreads();

    for (int ct = 0; ct < 16; ++ct) {
        const int c0 = ct * 64;
        const int ccol = w * 16 + lr;
        if constexpr (MODE == 1) {
            __syncthreads();
            for (int idx = tid; idx < 64 * 16; idx += 256) {
                const int cr = idx >> 4, d4 = (idx & 15) * 4;
                float4 rv = *(const float4*)(rhf + (size_t)(c0 + cr) * DM + n * DH + d4);
                unsigned short* p = usp(KR, SW128(cr, d4 * 2));
                p[0] = f2bf(rv.x); p[1] = f2bf(rv.y); p[2] = f2bf(rv.z); p[3] = f2bf(rv.w);
            }
            __syncthreads();
        }
        f32x4 acc = {0.f, 0.f, 0.f, 0.f};
#pragma unroll
        for (int kh = 0; kh < 2; ++kh) {
            short8 a = ld8(QV, SW128(lr, (kh * 32 + lg * 8) * 2));
            short8 bb;
            if constexpr (MODE == 0)
                bb = *(const short8*)(rhb + ((size_t)n * L + c0 + ccol) * DH + kh * 32 + lg * 8);
            else
                bb = ld8(KR, SW128(ccol, (kh * 32 + lg * 8) * 2));
            acc = __builtin_amdgcn_mfma_f32_16x16x32_bf16(a, bb, acc, 0, 0, 0);
        }
#pragma unroll
        for (int r2 = 0; r2 < 4; ++r2)
            BDp[(lg * 4 + r2) * BDP_ST + c0 + ccol] = f2h(acc[r2]);
        {
            const int col = tid >> 2, kq = (tid & 3) * 16;
            float s16 = 0.f;
#pragma unroll
            for (int kk = 0; kk < 16; kk += 8) {
                short8 qa = ld8(QV, SW128(16, (kq + kk) * 2));
                short8 ra;
                if constexpr (MODE == 0)
                    ra = *(const short8*)(rhb + ((size_t)n * L + c0 + col) * DH + kq + kk);
                else
                    ra = ld8(KR, SW128(col, (kq + kk) * 2));
#pragma unroll
                for (int e = 0; e < 8; ++e)
                    s16 = fmaf(bf2f((unsigned short)qa[e]), bf2f((unsigned short)ra[e]), s16);
            }
            s16 += __shfl_xor(s16, 1);
            s16 += __shfl_xor(s16, 2);
            if ((tid & 3) == 0) BDp[16 * BDP_ST + c0 + col] = f2h(s16);
        }
    }

    const int jloc = w * 16 + lr;
    __syncthreads();

    f32x4 pv = {0.f, 0.f, 0.f, 0.f};
    float dl[4] = {0.f, 0.f, 0.f, 0.f};
    float tmp[4][NJT];
#pragma unroll
    for (int jt = 0; jt < NJT; ++jt) {
        const int j0 = jt * 64;
        const int gj = j0 + jloc;
        const int cur = jt & 1;
        if constexpr (MODE == 1) {
            __syncthreads();
            for (int idx = tid; idx < 64 * 16; idx += 256) {
                const int jr = idx >> 4, d4 = (idx & 15) * 4;
                const size_t src = ((size_t)(j0 + jr) * BATCH + b) * DM + n * DH + d4;
                float4 kv = *(const float4*)(Kg + src);
                unsigned short* p = usp(KR, SW128(jr, d4 * 2));
                p[0] = f2bf(kv.x); p[1] = f2bf(kv.y); p[2] = f2bf(kv.z); p[3] = f2bf(kv.w);
                float4 vv4 = *(const float4*)(Vg + src);
                *usp(VT, SW128(d4 + 0, jr * 2)) = f2bf(vv4.x);
                *usp(VT, SW128(d4 + 1, jr * 2)) = f2bf(vv4.y);
                *usp(VT, SW128(d4 + 2, jr * 2)) = f2bf(vv4.z);
                *usp(VT, SW128(d4 + 3, jr * 2)) = f2bf(vv4.w);
            }
            __syncthreads();
        }
        f32x4 acc = {0.f, 0.f, 0.f, 0.f};
#pragma unroll
        for (int kh = 0; kh < 2; ++kh) {
            short8 a = ld8(QU, SW128(lr, (kh * 32 + lg * 8) * 2));
            short8 bb;
            if constexpr (MODE == 0)
                bb = *(const short8*)(Kbf + ((size_t)bn * L + gj) * DH + kh * 32 + lg * 8);
            else
                bb = ld8(KR, SW128(jloc, (kh * 32 + lg * 8) * 2));
            acc = __builtin_amdgcn_mfma_f32_16x16x32_bf16(a, bb, acc, 0, 0, 0);
        }
        const bool msk = mblk[gj] != 0;
#pragma unroll
        for (int r2 = 0; r2 < 4; ++r2) {
            const int il = lg * 4 + r2;
            const int gi = i0 + il;
            const int t = gj - gi;
            float bd = 0.f;
            if (t != 1) {
                const int c = (t <= 0) ? (L - 1 + t) : (t - 2);
                bd = h2f(BDp[(il + (t >= 1 ? 1 : 0)) * BDP_ST + c]);
            }
            float s = acc[r2] + bd;
            if (msk) s = -1e9f;
            const float wgt = __expf(fminf(s, 80.f));
            dl[r2] += wgt;
            tmp[r2][jt] = wgt;
            *usp(Wt[cur], SW128(il, jloc * 2)) = f2bf(wgt);
        }
        __syncthreads();
#pragma unroll
        for (int kh = 0; kh < 2; ++kh) {
            short8 a = ld8(Wt[cur], SW128(lr, (kh * 32 + lg * 8) * 2));
            short8 bb;
            if constexpr (MODE == 0)
                bb = *(const short8*)(Vtb + ((size_t)bn * DH + jloc) * L + j0 + kh * 32 + lg * 8);
            else
                bb = ld8(VT, SW128(jloc, (kh * 32 + lg * 8) * 2));
            pv = __builtin_amdgcn_mfma_f32_16x16x32_bf16(a, bb, pv, 0, 0, 0);
        }
    }

#pragma unroll
    for (int r2 = 0; r2 < 4; ++r2) {
        float d = dl[r2];
        d += __shfl_xor(d, 1); d += __shfl_xor(d, 2);
        d += __shfl_xor(d, 4); d += __shfl_xor(d, 8);
        if (lr == 0) denomP[w][lg * 4 + r2] = d;
    }
    __syncthreads();
    if (tid < 16)
        rdenom[tid] = 1.f / (denomP[0][tid] + denomP[1][tid] + denomP[2][tid] + denomP[3][tid]);
    __syncthreads();

#pragma unroll
    for (int r2 = 0; r2 < 4; ++r2) {
        const int il = lg * 4 + r2;
        out[((size_t)(i0 + il) * BATCH + b) * DM + n * DH + w * 16 + lr] = pv[r2] * rdenom[il];
    }
#pragma unroll
    for (int r2 = 0; r2 < 4; ++r2) {
        const int il = lg * 4 + r2;
        const float rs = rdenom[il] * (1.f / 16.f);
#pragma unroll
        for (int jt = 0; jt < NJT; ++jt)
            atomicAdd(wm_out + ((size_t)(i0 + il) * L + jt * 64 + jloc) * BATCH + b,
                      tmp[r2][jt] * rs);
    }
}

// ---------------------------------------------------------------------------
extern "C" void kernel_launch(void* const* d_in, const int* in_sizes, int n_in,
                              void* d_out, int out_size, void* d_ws, size_t ws_size,
                              hipStream_t stream)
{
    (void)in_sizes; (void)n_in; (void)out_size;
    const float* q   = (const float*)d_in[0];
    const float* K   = (const float*)d_in[1];
    const float* V   = (const float*)d_in[2];
    const unsigned char* mask = (const unsigned char*)d_in[3];
    const float* r   = (const float*)d_in[4];
    const float* u   = (const float*)d_in[5];
    const float* v   = (const float*)d_in[6];
    const float* Wr  = (const float*)d_in[7];
    const float* br  = (const float*)d_in[8];

    float* out = (float*)d_out;                    // (1024, 4, 1024)
    float* wm  = out + (size_t)L * BATCH * DM;     // (1024, 1024, 4)

    const size_t kvbytes = (size_t)BATCH * NH * L * DH * 2;   // 8 MB each
    const size_t rhbytes = (size_t)NH * L * DH * 2;           // 2 MB
    const size_t wmbytes = (size_t)BATCH * NH * L * L * 2;    // 134 MB
    const size_t rdbytes = (size_t)BATCH * NH * L * 4;        // 256 KB

    if (ws_size >= 2 * kvbytes + rhbytes + wmbytes + rdbytes) {
        unsigned short* Kbf = (unsigned short*)d_ws;
        unsigned short* Vtb = Kbf + kvbytes / 2;
        unsigned short* rhb = Vtb + kvbytes / 2;
        unsigned short* Wws = rhb + rhbytes / 2;
        float* rdeng = (float*)(Wws + wmbytes / 2);
        rh_gemm_mfma<<<dim3(16, 16), 256, 0, stream>>>(r, Wr, br, rhb);
        prepass_kernel<<<dim3(16, 4, 16), 256, 0, stream>>>(K, V, Kbf, Vtb);
        attn_fused<<<dim3(4096), 256, 0, stream>>>(
            q, Kbf, Vtb, mask, u, v, rhb, out, Wws, rdeng);
        wm_reduce_kernel<<<dim3(64, 4, 4), 256, 0, stream>>>(Wws, rdeng, wm);
    } else if (ws_size >= 2 * kvbytes + rhbytes) {
        hipMemsetAsync(wm, 0, (size_t)L * L * BATCH * sizeof(float), stream);
        unsigned short* Kbf = (unsigned short*)d_ws;
        unsigned short* Vtb = Kbf + kvbytes / 2;
        unsigned short* rhb = Vtb + kvbytes / 2;
        rh_gemm_mfma<<<dim3(16, 16), 256, 0, stream>>>(r, Wr, br, rhb);
        prepass_kernel<<<dim3(16, 4, 16), 256, 0, stream>>>(K, V, Kbf, Vtb);
        attn_legacy<0><<<dim3(64, 4, 16), 256, 0, stream>>>(
            q, Kbf, Vtb, mask, u, v, rhb, out, wm);
    } else {
        hipMemsetAsync(wm, 0, (size_t)L * L * BATCH * sizeof(float), stream);
        float* rhf = (float*)d_ws;
        rh_gemm_kernel<<<dim3(16, 16), 256, 0, stream>>>(r, Wr, br, rhf);
        attn_legacy<1><<<dim3(64, 4, 16), 256, 0, stream>>>(
            q, K, V, mask, u, v, rhf, out, wm);
    }
}

// Round 12
// 287.484 us; speedup vs baseline: 1.4673x; 1.0118x over previous
//
#include <hip/hip_runtime.h>
#include <hip/hip_fp16.h>
#include <stdint.h>

// Transformer-XL relative attention, round 12: I-cache-resident rolled loops.
// L=qlen=klen=1024, BATCH=4, NH=16, DH=64, DM=1024.
//
// r7-r11 attn pinned at ~237us, ~94% stall, invariant to barriers/occupancy/
// prefetch/L2-locality => front-end (I-fetch) theory: body was ~40KB straight-
// line code > 32KB I-cache. r12: BD-build and j-loop ROLLED (#pragma unroll 1)
// with 2-chunk bodies; ring-2 prefetch uses statically-named regs (kfA/kfB,
// rbA/rbB) to avoid scratch (runtime-indexed ext_vector arrays).
// All math identical to verified r11: swapped-S (mfma(K,Q)), shifted-BD,
// per-wave LDS Wt round-trip, XCD-pane swizzle, coalesced W_ws+wm_reduce.

#define L 1024
#define BATCH 4
#define NH 16
#define DH 64
#define DM 1024
#define TI 16
#define NJT 16
#define BD_ST 1028
#define BDP_ST 1032
#define WT_ST 40
#define SCALE 0.125f
#define CS 0.18033688011112042f   // 0.125 * log2(e)

typedef __attribute__((ext_vector_type(8))) short short8;
typedef __attribute__((ext_vector_type(4))) float f32x4;

static __device__ __forceinline__ unsigned short f2bf(float f) {
    union { float f; unsigned int u; } x; x.f = f;
    return (unsigned short)((x.u + 0x7fffu + ((x.u >> 16) & 1u)) >> 16);  // RNE
}
static __device__ __forceinline__ float bf2f(unsigned short h) {
    union { unsigned int u; float f; } x; x.u = ((unsigned int)h) << 16;
    return x.f;
}
static __device__ __forceinline__ unsigned short f2h(float f) {
    __half h = __float2half(f);
    union { __half h; unsigned short s; } x; x.h = h; return x.s;
}
static __device__ __forceinline__ float h2f(unsigned short s) {
    union { __half h; unsigned short s; } x; x.s = s; return __half2float(x.h);
}
static __device__ __forceinline__ unsigned short* usp(void* base, int byteoff) {
    return (unsigned short*)((char*)base + byteoff);
}
static __device__ __forceinline__ short8 ld8(const void* base, int byteoff) {
    return *(const short8*)((const char*)base + byteoff);
}
static __device__ __forceinline__ float fexp2(float x) {
#if __has_builtin(__builtin_amdgcn_exp2f)
    return __builtin_amdgcn_exp2f(x);
#else
    return __expf(x * 0.6931471805599453f);
#endif
}
#define SW128(row, colByte) ((((row) * 128) + (colByte)) ^ (((row) & 7) << 4))

// ---------------------------------------------------------------------------
// K1a (main): rh = r @ Wr^T + br via bf16 MFMA -> rhb [n][c][d] bf16.
// ---------------------------------------------------------------------------
__global__ __launch_bounds__(256) void rh_gemm_mfma(
    const float* __restrict__ r, const float* __restrict__ Wr,
    const float* __restrict__ br, unsigned short* __restrict__ rhb)
{
    __shared__ unsigned short rT[64 * 64];
    __shared__ unsigned short wT[64 * 64];
    const int c0 = blockIdx.x * 64, m0 = blockIdx.y * 64;
    const int tid = threadIdx.x;
    const int w = tid >> 6, lane = tid & 63, lr = lane & 15, lg = lane >> 4;
    f32x4 acc[4] = {};

    for (int kt = 0; kt < 16; ++kt) {
        const int k0 = kt * 64;
        __syncthreads();
        const int row = tid >> 2, cb = (tid & 3) * 16;
#pragma unroll
        for (int q4 = 0; q4 < 4; ++q4) {
            float4 rv = *(const float4*)(r + (size_t)(c0 + row) * DM + k0 + cb + q4 * 4);
            unsigned short* p = usp(rT, SW128(row, (cb + q4 * 4) * 2));
            p[0] = f2bf(rv.x); p[1] = f2bf(rv.y); p[2] = f2bf(rv.z); p[3] = f2bf(rv.w);
            float4 wv = *(const float4*)(Wr + (size_t)(m0 + row) * DM + k0 + cb + q4 * 4);
            unsigned short* pw = usp(wT, SW128(row, (cb + q4 * 4) * 2));
            pw[0] = f2bf(wv.x); pw[1] = f2bf(wv.y); pw[2] = f2bf(wv.z); pw[3] = f2bf(wv.w);
        }
        __syncthreads();
#pragma unroll
        for (int mch = 0; mch < 4; ++mch)
#pragma unroll
            for (int kh = 0; kh < 2; ++kh) {
                short8 a  = ld8(rT, SW128(w * 16 + lr,   (kh * 32 + lg * 8) * 2));
                short8 bb = ld8(wT, SW128(mch * 16 + lr, (kh * 32 + lg * 8) * 2));
                acc[mch] = __builtin_amdgcn_mfma_f32_16x16x32_bf16(a, bb, acc[mch], 0, 0, 0);
            }
    }
#pragma unroll
    for (int mch = 0; mch < 4; ++mch)
#pragma unroll
        for (int r2 = 0; r2 < 4; ++r2) {
            const int c = c0 + w * 16 + lg * 4 + r2;
            const int d = mch * 16 + lr;
            const float val = acc[mch][r2] + br[m0 + d];
            rhb[((size_t)blockIdx.y * L + c) * DH + d] = f2bf(val);
        }
}

// ---------------------------------------------------------------------------
// K1b (fallback): f32 rh for MODE1.
// ---------------------------------------------------------------------------
__global__ __launch_bounds__(256) void rh_gemm_kernel(
    const float* __restrict__ r, const float* __restrict__ Wr,
    const float* __restrict__ br, float* __restrict__ rhf)
{
    __shared__ float As[16][65];
    __shared__ float Bs[16][65];
    const int j0 = blockIdx.x * 64;
    const int m0 = blockIdx.y * 64;
    const int tid = threadIdx.x;
    const int ty = tid >> 4, tx = tid & 15;
    float acc[4][4] = {};

    for (int k0 = 0; k0 < DM; k0 += 16) {
        const int row = tid >> 2, c4 = (tid & 3) << 2;
        float4 av = *(const float4*)(r  + (size_t)(j0 + row) * DM + k0 + c4);
        float4 bv = *(const float4*)(Wr + (size_t)(m0 + row) * DM + k0 + c4);
        __syncthreads();
        As[c4 + 0][row] = av.x; As[c4 + 1][row] = av.y;
        As[c4 + 2][row] = av.z; As[c4 + 3][row] = av.w;
        Bs[c4 + 0][row] = bv.x; Bs[c4 + 1][row] = bv.y;
        Bs[c4 + 2][row] = bv.z; Bs[c4 + 3][row] = bv.w;
        __syncthreads();
#pragma unroll
        for (int k = 0; k < 16; ++k) {
            float a[4], bb[4];
#pragma unroll
            for (int t = 0; t < 4; ++t) { a[t] = As[k][ty * 4 + t]; bb[t] = Bs[k][tx * 4 + t]; }
#pragma unroll
            for (int ii = 0; ii < 4; ++ii)
#pragma unroll
                for (int jj = 0; jj < 4; ++jj)
                    acc[ii][jj] = fmaf(a[ii], bb[jj], acc[ii][jj]);
        }
    }
#pragma unroll
    for (int ii = 0; ii < 4; ++ii) {
        const int row = j0 + ty * 4 + ii;
#pragma unroll
        for (int jj = 0; jj < 4; ++jj) {
            const int col = m0 + tx * 4 + jj;
            rhf[(size_t)row * DM + col] = acc[ii][jj] + br[col];
        }
    }
}

// ---------------------------------------------------------------------------
// Prepass: K f32[j][b][m] -> bf16 Kbf[b][n][j][d]; V -> bf16 Vtb[b][n][d][j].
// ---------------------------------------------------------------------------
__global__ __launch_bounds__(256) void prepass_kernel(
    const float* __restrict__ Kg, const float* __restrict__ Vg,
    unsigned short* __restrict__ Kbf, unsigned short* __restrict__ Vtb)
{
    __shared__ unsigned short tile[64][80];
    const int j0 = blockIdx.x * 64;
    const int b = blockIdx.y, n = blockIdx.z;
    const int bn = b * NH + n;
    const int tid = threadIdx.x;

    for (int idx = tid; idx < 64 * 16; idx += 256) {
        const int jr = idx >> 4, s4 = (idx & 15) * 4;
        const size_t src = ((size_t)(j0 + jr) * BATCH + b) * DM + n * DH + s4;
        float4 kv = *(const float4*)(Kg + src);
        ushort4 o;
        o.x = f2bf(kv.x); o.y = f2bf(kv.y); o.z = f2bf(kv.z); o.w = f2bf(kv.w);
        *(ushort4*)(Kbf + ((size_t)bn * L + j0 + jr) * DH + s4) = o;
        float4 vv4 = *(const float4*)(Vg + src);
        tile[s4 + 0][jr] = f2bf(vv4.x); tile[s4 + 1][jr] = f2bf(vv4.y);
        tile[s4 + 2][jr] = f2bf(vv4.z); tile[s4 + 3][jr] = f2bf(vv4.w);
    }
    __syncthreads();
    for (int idx = tid; idx < 64 * 8; idx += 256) {
        const int d = idx >> 3, p8 = (idx & 7) * 8;
        short8 o = *(const short8*)&tile[d][p8];
        *(short8*)(Vtb + ((size_t)bn * DH + d) * L + j0 + p8) = o;
    }
}

// ---------------------------------------------------------------------------
// wm reduce, READ-COALESCED (verified r11): grid (ib=64, gcq=4, b=4).
// ---------------------------------------------------------------------------
__global__ __launch_bounds__(256) void wm_reduce_kernel(
    const unsigned short* __restrict__ Wf, const float* __restrict__ rdeng,
    float* __restrict__ wm_out)
{
    const int ib = blockIdx.x;
    const int gq = blockIdx.y;
    const int b  = blockIdx.z;
    const int tid = threadIdx.x;
    const int w = tid >> 6, lane = tid & 63, lr = lane & 15, lg = lane >> 4;
    const int i = ib * 16 + lr;

    float rd[NH];
#pragma unroll
    for (int n = 0; n < NH; ++n)
        rd[n] = rdeng[((size_t)(b * NH + n) << 10) + i];

#pragma unroll
    for (int k = 0; k < 4; ++k) {
        const int gc = gq * 16 + w * 4 + k;
        float a0 = 0.f, a1 = 0.f, a2 = 0.f, a3 = 0.f;
#pragma unroll
        for (int n = 0; n < NH; ++n) {
            const int bn = b * NH + n;
            ushort4 wv = *(const ushort4*)(Wf +
                (((size_t)(bn * 64 + ib) * 64 + gc) * 64 + lane) * 4);
            a0 += bf2f(wv.x) * rd[n]; a1 += bf2f(wv.y) * rd[n];
            a2 += bf2f(wv.z) * rd[n]; a3 += bf2f(wv.w) * rd[n];
        }
        const size_t o = ((size_t)i * L + gc * 16 + lg * 4) * BATCH + b;
        wm_out[o]             = a0;
        wm_out[o + BATCH]     = a1;
        wm_out[o + 2 * BATCH] = a2;
        wm_out[o + 3 * BATCH] = a3;
    }
}

// ---- chunk body for the j-loop (statically-named prefetch regs) -----------
#define CHUNK_BODY(CHUNK, JC, KF0, KF1)                                       \
    {                                                                         \
        const int chunk_ = (CHUNK);                                           \
        const int jc_ = (JC);                                                 \
        short8 nk0_, nk1_;                                                    \
        const bool pf_ = (chunk_ + 2) < 16;                                   \
        if (pf_) {                                                            \
            const int jn_ = jwbase + (chunk_ + 2) * 16 + lr;                  \
            nk0_ = *(const short8*)(Kpane + (size_t)jn_ * DH + lg * 8);       \
            nk1_ = *(const short8*)(Kpane + (size_t)jn_ * DH + 32 + lg * 8);  \
        }                                                                     \
        f32x4 acc_ = {0.f, 0.f, 0.f, 0.f};                                    \
        acc_ = __builtin_amdgcn_mfma_f32_16x16x32_bf16(KF0, qu_a[0], acc_, 0, 0, 0); \
        acc_ = __builtin_amdgcn_mfma_f32_16x16x32_bf16(KF1, qu_a[1], acc_, 0, 0, 0); \
        const int jq_ = jc_ + lg * 4;                                         \
        const unsigned int m4_ = *(const unsigned int*)&mblk[jq_];            \
        const ushort4 bdq_ = *(const ushort4*)&BD[lr * BD_ST + jq_];          \
        ushort4 wpack_;                                                       \
        _Pragma("unroll")                                                     \
        for (int r2 = 0; r2 < 4; ++r2) {                                      \
            const unsigned short bdh_ =                                       \
                (r2 == 0) ? bdq_.x : (r2 == 1) ? bdq_.y : (r2 == 2) ? bdq_.z : bdq_.w; \
            const float mo_ = ((m4_ >> (8 * r2)) & 0xffu) ? -1e9f : 0.f;      \
            const float s_ = fminf(acc_[r2] + h2f(bdh_) + mo_, 126.f);        \
            const float wg_ = fexp2(s_);                                      \
            dl += wg_;                                                        \
            ((unsigned short*)&wpack_)[r2] = f2bf(wg_);                       \
        }                                                                     \
        *(ushort4*)(WtW + lr * WT_ST + ((jc_ >> 4) & 1) * 16 + lg * 4) = wpack_; \
        *(ushort4*)(W_ws + wsbase + (((size_t)(jc_ >> 4)) * 64 + lane) * 4) = wpack_; \
        if (pf_) { KF0 = nk0_; KF1 = nk1_; }                                  \
    }

// ---- BD-build body (statically-named prefetch regs) -----------------------
#define BD_BODY(CT, RB0, RB1)                                                 \
    {                                                                         \
        const int ct_ = (CT);                                                 \
        const int c0_ = ct_ * 64;                                             \
        short8 nr0_, nr1_;                                                    \
        const bool pf_ = (ct_ + 2) < 16;                                      \
        if (pf_) {                                                            \
            nr0_ = *(const short8*)(rpane + (size_t)((ct_ + 2) * 64 + ccol) * DH + lg * 8); \
            nr1_ = *(const short8*)(rpane + (size_t)((ct_ + 2) * 64 + ccol) * DH + 32 + lg * 8); \
        }                                                                     \
        f32x4 acc_ = {0.f, 0.f, 0.f, 0.f};                                    \
        acc_ = __builtin_amdgcn_mfma_f32_16x16x32_bf16(qv_a[0], RB0, acc_, 0, 0, 0); \
        acc_ = __builtin_amdgcn_mfma_f32_16x16x32_bf16(qv_a[1], RB1, acc_, 0, 0, 0); \
        const int c_ = c0_ + ccol;                                            \
        _Pragma("unroll")                                                     \
        for (int r2 = 0; r2 < 4; ++r2) {                                      \
            const int ilp_ = lg * 4 + r2;                                     \
            const unsigned short hv_ = f2h(acc_[r2]);                         \
            const int j1_ = c_ + i0 + ilp_ - 1023;                            \
            if (j1_ >= 0) BD[ilp_ * BD_ST + j1_] = hv_;                       \
            const int j2_ = c_ + i0 + ilp_ + 1;                               \
            if (ilp_ >= 1 && j2_ <= 1023) BD[(ilp_ - 1) * BD_ST + j2_] = hv_; \
        }                                                                     \
        {   /* row 16 (i+1 shift source for row 15) */                        \
            short8 ra0_ = *(const short8*)(rpane + (size_t)(c0_ + col16) * DH + kq); \
            short8 ra1_ = *(const short8*)(rpane + (size_t)(c0_ + col16) * DH + kq + 8); \
            float s16_ = 0.f;                                                 \
            _Pragma("unroll")                                                 \
            for (int e = 0; e < 8; ++e) {                                     \
                s16_ = fmaf(qv16[e],     bf2f((unsigned short)ra0_[e]), s16_);\
                s16_ = fmaf(qv16[e + 8], bf2f((unsigned short)ra1_[e]), s16_);\
            }                                                                 \
            s16_ += __shfl_xor(s16_, 1);                                      \
            s16_ += __shfl_xor(s16_, 2);                                      \
            const int j16_ = c0_ + col16 + i0 + 17;                           \
            if ((tid & 3) == 0 && j16_ <= 1023)                               \
                BD[15 * BD_ST + j16_] = f2h(s16_);                            \
        }                                                                     \
        if (pf_) { RB0 = nr0_; RB1 = nr1_; }                                  \
    }

// ---------------------------------------------------------------------------
// K2 (main): swapped-S, shifted-BD, LDS-Wt PV, rolled loops (I-cache fit).
// ---------------------------------------------------------------------------
__global__ __launch_bounds__(256, 4) void attn_fused(
    const float* __restrict__ q,
    const unsigned short* __restrict__ Kbf, const unsigned short* __restrict__ Vtb,
    const unsigned char* __restrict__ maskp,
    const float* __restrict__ uu, const float* __restrict__ vvp,
    const unsigned short* __restrict__ rhb,
    float* __restrict__ out, unsigned short* __restrict__ W_ws,
    float* __restrict__ rdeng)
{
    __shared__ __align__(16) unsigned short BD[16 * BD_ST];
    __shared__ __align__(16) unsigned short Wt[4][16 * WT_ST];
    __shared__ unsigned char mblk[L];
    __shared__ float denomP[4][16];
    __shared__ float rdenom[16];
    __shared__ int mflags;

    // XCD-pane swizzle (verified r8)
    const int lin = blockIdx.x;
    const int xcd = lin & 7, idx = lin >> 3;
    const int ib  = idx & 63;
    const int pane = xcd * 8 + (idx >> 6);
    const int b = pane >> 4, n = pane & 15;
    const int i0 = ib * 16;
    const int bn = pane;

    const int tid = threadIdx.x;
    const int w = tid >> 6, lane = tid & 63, lr = lane & 15, lg = lane >> 4;

    // ---- mask dtype detection (verified r2) + staging ----
    if (tid == 0) mflags = 0;
    __syncthreads();
    {
        int local = 0;
#pragma unroll 1
        for (int ww = tid; ww < 1024; ww += 256) {
            const unsigned int word = ((const unsigned int*)maskp)[ww];
            if (word == 0x3f800000u) local |= 1;
            else if (word & 0xffffff00u) local |= 2;
        }
        if (local) atomicOr(&mflags, local);
    }
    __syncthreads();
    {
        const int mtype = (mflags & 1) ? 2 : ((mflags & 2) ? 1 : 0);
#pragma unroll 1
        for (int j = tid; j < L; j += 256) {
            bool mv;
            if (mtype == 2)      mv = ((const float*)maskp)[j * BATCH + b] != 0.f;
            else if (mtype == 1) mv = maskp[j * BATCH + b] != 0;
            else                 mv = ((const int*)maskp)[j * BATCH + b] != 0;
            mblk[j] = mv ? 1 : 0;
        }
    }
    // zero the t==1 diagonal
    if (tid < 16) {
        const int jz = i0 + tid + 1;
        if (jz <= 1023) BD[tid * BD_ST + jz] = 0;
    }

    // ---- Q fragments in registers (x 0.125*log2e) ----
    const float* qrow = q + ((size_t)(i0 + lr) * BATCH + b) * DM + n * DH;
    const float* urow = uu + n * DH;
    const float* vrow = vvp + n * DH;
    short8 qu_a[2], qv_a[2];
#pragma unroll
    for (int kh = 0; kh < 2; ++kh) {
        const int kb = kh * 32 + lg * 8;
        float4 qa = *(const float4*)(qrow + kb), qb = *(const float4*)(qrow + kb + 4);
        float4 ua = *(const float4*)(urow + kb), ub = *(const float4*)(urow + kb + 4);
        float4 va = *(const float4*)(vrow + kb), vb = *(const float4*)(vrow + kb + 4);
        short8 su, sv;
        su[0] = (short)f2bf((qa.x + ua.x) * CS); su[1] = (short)f2bf((qa.y + ua.y) * CS);
        su[2] = (short)f2bf((qa.z + ua.z) * CS); su[3] = (short)f2bf((qa.w + ua.w) * CS);
        su[4] = (short)f2bf((qb.x + ub.x) * CS); su[5] = (short)f2bf((qb.y + ub.y) * CS);
        su[6] = (short)f2bf((qb.z + ub.z) * CS); su[7] = (short)f2bf((qb.w + ub.w) * CS);
        sv[0] = (short)f2bf((qa.x + va.x) * CS); sv[1] = (short)f2bf((qa.y + va.y) * CS);
        sv[2] = (short)f2bf((qa.z + va.z) * CS); sv[3] = (short)f2bf((qa.w + va.w) * CS);
        sv[4] = (short)f2bf((qb.x + vb.x) * CS); sv[5] = (short)f2bf((qb.y + vb.y) * CS);
        sv[6] = (short)f2bf((qb.z + vb.z) * CS); sv[7] = (short)f2bf((qb.w + vb.w) * CS);
        qu_a[kh] = su; qv_a[kh] = sv;
    }
    float qv16[16];
    {
        const int kq0 = (tid & 3) * 16;
        if (i0 + 16 < L) {
            const float* q16 = q + ((size_t)(i0 + 16) * BATCH + b) * DM + n * DH;
#pragma unroll
            for (int e4 = 0; e4 < 4; ++e4) {
                float4 qa = *(const float4*)(q16 + kq0 + e4 * 4);
                float4 va = *(const float4*)(vrow + kq0 + e4 * 4);
                qv16[e4 * 4 + 0] = (qa.x + va.x) * CS; qv16[e4 * 4 + 1] = (qa.y + va.y) * CS;
                qv16[e4 * 4 + 2] = (qa.z + va.z) * CS; qv16[e4 * 4 + 3] = (qa.w + va.w) * CS;
            }
        } else {
#pragma unroll
            for (int e = 0; e < 16; ++e) qv16[e] = 0.f;
        }
    }

    // ============== BD build: rolled, 2 c-tiles per iteration ==============
    {
        const unsigned short* rpane = rhb + (size_t)n * L * DH;
        const int ccol = w * 16 + lr;
        const int col16 = tid >> 2;
        const int kq = (tid & 3) * 16;
        short8 rbA0, rbA1, rbB0, rbB1;
        rbA0 = *(const short8*)(rpane + (size_t)ccol * DH + lg * 8);
        rbA1 = *(const short8*)(rpane + (size_t)ccol * DH + 32 + lg * 8);
        rbB0 = *(const short8*)(rpane + (size_t)(64 + ccol) * DH + lg * 8);
        rbB1 = *(const short8*)(rpane + (size_t)(64 + ccol) * DH + 32 + lg * 8);
#pragma unroll 1
        for (int ct2 = 0; ct2 < 8; ++ct2) {
            BD_BODY(ct2 * 2,     rbA0, rbA1);
            BD_BODY(ct2 * 2 + 1, rbB0, rbB1);
        }
    }
    __syncthreads();   // BD + mblk visible to all

    // ============== j-loop: rolled, 1 window (2 chunks) per iteration ======
    const unsigned short* Kpane = Kbf + (size_t)bn * L * DH;
    const unsigned short* Vpane = Vtb + (size_t)bn * DH * L;
    const int jwbase = w * 256;
    unsigned short* WtW = &Wt[w][0];
    f32x4 pv[4] = {};
    float dl = 0.f;
    const size_t wsbase = (((size_t)bn * 64 + ib) * 64) * 64 * 4;

    short8 kfA0, kfA1, kfB0, kfB1;
    kfA0 = *(const short8*)(Kpane + (size_t)(jwbase + lr) * DH + lg * 8);
    kfA1 = *(const short8*)(Kpane + (size_t)(jwbase + lr) * DH + 32 + lg * 8);
    kfB0 = *(const short8*)(Kpane + (size_t)(jwbase + 16 + lr) * DH + lg * 8);
    kfB1 = *(const short8*)(Kpane + (size_t)(jwbase + 16 + lr) * DH + 32 + lg * 8);

#pragma unroll 1
    for (int wi = 0; wi < 8; ++wi) {               // window = 32 j
        const int jbase32 = jwbase + wi * 32;
        short8 vf0, vf1, vf2, vf3;
        vf0 = *(const short8*)(Vpane + (size_t)(0 * 16 + lr) * L + jbase32 + lg * 8);
        vf1 = *(const short8*)(Vpane + (size_t)(1 * 16 + lr) * L + jbase32 + lg * 8);
        vf2 = *(const short8*)(Vpane + (size_t)(2 * 16 + lr) * L + jbase32 + lg * 8);
        vf3 = *(const short8*)(Vpane + (size_t)(3 * 16 + lr) * L + jbase32 + lg * 8);
        CHUNK_BODY(wi * 2,     jbase32,      kfA0, kfA1);
        CHUNK_BODY(wi * 2 + 1, jbase32 + 16, kfB0, kfB1);
        // PV: A-frag from this wave's Wt (in-wave ds ordering only)
        short8 afrag = *(const short8*)(WtW + lr * WT_ST + lg * 8);
        pv[0] = __builtin_amdgcn_mfma_f32_16x16x32_bf16(afrag, vf0, pv[0], 0, 0, 0);
        pv[1] = __builtin_amdgcn_mfma_f32_16x16x32_bf16(afrag, vf1, pv[1], 0, 0, 0);
        pv[2] = __builtin_amdgcn_mfma_f32_16x16x32_bf16(afrag, vf2, pv[2], 0, 0, 0);
        pv[3] = __builtin_amdgcn_mfma_f32_16x16x32_bf16(afrag, vf3, pv[3], 0, 0, 0);
    }

    // ---- denominators (row lr): reduce across lg groups ----
    dl += __shfl_xor(dl, 16, 64);
    dl += __shfl_xor(dl, 32, 64);
    if (lane < 16) denomP[w][lane] = dl;
    __syncthreads();                       // all BD (fp16) reads done

    // pv partials into BD region (reused as f32 scratch, per-wave private)
    {
        float* pvw = (float*)BD + w * 1024;
#pragma unroll
        for (int dch = 0; dch < 4; ++dch)
#pragma unroll
            for (int r2 = 0; r2 < 4; ++r2)
                pvw[(lg * 4 + r2) * 64 + dch * 16 + lr] = pv[dch][r2];
    }
    if (tid < 16) {
        const float dn = denomP[0][tid] + denomP[1][tid] + denomP[2][tid] + denomP[3][tid];
        rdenom[tid] = 1.f / dn;
        rdeng[((size_t)bn << 10) + i0 + tid] = 1.f / (dn * 16.f);
    }
    __syncthreads();

    // ---- out = (sum_w pv_w) * rdenom ----
    {
        const float* pvwAll = (const float*)BD;
        const int il = tid >> 4, d0 = (tid & 15) * 4;
        float4 o  = *(const float4*)(pvwAll + 0 * 1024 + il * 64 + d0);
        float4 o1 = *(const float4*)(pvwAll + 1 * 1024 + il * 64 + d0);
        float4 o2 = *(const float4*)(pvwAll + 2 * 1024 + il * 64 + d0);
        float4 o3 = *(const float4*)(pvwAll + 3 * 1024 + il * 64 + d0);
        const float rs = rdenom[il];
        o.x = (o.x + o1.x + o2.x + o3.x) * rs;
        o.y = (o.y + o1.y + o2.y + o3.y) * rs;
        o.z = (o.z + o1.z + o2.z + o3.z) * rs;
        o.w = (o.w + o1.w + o2.w + o3.w) * rs;
        *(float4*)(out + ((size_t)(i0 + il) * BATCH + b) * DM + n * DH + d0) = o;
    }
}

// ---------------------------------------------------------------------------
// Legacy K2 (round-6 structure) for fallback paths; atomic wm accumulation.
// ---------------------------------------------------------------------------
template<int MODE>
__global__ __launch_bounds__(256, 2) void attn_legacy(
    const float* __restrict__ q,
    const void* __restrict__ Kp, const void* __restrict__ Vp,
    const unsigned char* __restrict__ maskp,
    const float* __restrict__ uu, const float* __restrict__ vvp,
    const void* __restrict__ rhp,
    float* __restrict__ out, float* __restrict__ wm_out)
{
    __shared__ unsigned short QU[16 * 64];
    __shared__ unsigned short QV[17 * 64];
    __shared__ unsigned short KR[(MODE == 1) ? 64 * 64 : 8];
    __shared__ unsigned short VT[(MODE == 1) ? 64 * 64 : 8];
    __shared__ unsigned short BDp[17 * BDP_ST];
    __shared__ unsigned short Wt[2][16 * 64];
    __shared__ unsigned char mblk[L];
    __shared__ float denomP[4][16];
    __shared__ float rdenom[16];
    __shared__ int mflags;

    const int i0 = blockIdx.x * TI;
    const int b  = blockIdx.y;
    const int n  = blockIdx.z;
    const int bn = b * NH + n;
    const int tid = threadIdx.x;
    const int w = tid >> 6, lane = tid & 63, lr = lane & 15, lg = lane >> 4;

    const unsigned short* Kbf = (const unsigned short*)Kp;
    const unsigned short* Vtb = (const unsigned short*)Vp;
    const unsigned short* rhb = (const unsigned short*)rhp;
    const float* Kg  = (const float*)Kp;
    const float* Vg  = (const float*)Vp;
    const float* rhf = (const float*)rhp;

    if (tid == 0) mflags = 0;
    __syncthreads();
    {
        int local = 0;
        for (int ww = tid; ww < 1024; ww += 256) {
            const unsigned int word = ((const unsigned int*)maskp)[ww];
            if (word == 0x3f800000u) local |= 1;
            else if (word & 0xffffff00u) local |= 2;
        }
        if (local) atomicOr(&mflags, local);
    }
    __syncthreads();
    {
        const int mtype = (mflags & 1) ? 2 : ((mflags & 2) ? 1 : 0);
        for (int j = tid; j < L; j += 256) {
            bool mv;
            if (mtype == 2)      mv = ((const float*)maskp)[j * BATCH + b] != 0.f;
            else if (mtype == 1) mv = maskp[j * BATCH + b] != 0;
            else                 mv = ((const int*)maskp)[j * BATCH + b] != 0;
            mblk[j] = mv ? 1 : 0;
        }
    }
    for (int idx = tid; idx < 17 * 64; idx += 256) {
        const int row = idx >> 6, d = idx & 63;
        const int gi = i0 + row;
        const float qval = (gi < L) ? q[((size_t)gi * BATCH + b) * DM + n * DH + d] : 0.f;
        *usp(QV, SW128(row, d * 2)) = f2bf((qval + vvp[n * DH + d]) * SCALE);
        if (row < 16) *usp(QU, SW128(row, d * 2)) = f2bf((qval + uu[n * DH + d]) * SCALE);
    }
    __syncthreads();

    for (int ct = 0; ct < 16; ++ct) {
        const int c0 = ct * 64;
        const int ccol = w * 16 + lr;
        if constexpr (MODE == 1) {
            __syncthreads();
            for (int idx = tid; idx < 64 * 16; idx += 256) {
                const int cr = idx >> 4, d4 = (idx & 15) * 4;
                float4 rv = *(const float4*)(rhf + (size_t)(c0 + cr) * DM + n * DH + d4);
                unsigned short* p = usp(KR, SW128(cr, d4 * 2));
                p[0] = f2bf(rv.x); p[1] = f2bf(rv.y); p[2] = f2bf(rv.z); p[3] = f2bf(rv.w);
            }
            __syncthreads();
        }
        f32x4 acc = {0.f, 0.f, 0.f, 0.f};
#pragma unroll
        for (int kh = 0; kh < 2; ++kh) {
            short8 a = ld8(QV, SW128(lr, (kh * 32 + lg * 8) * 2));
            short8 bb;
            if constexpr (MODE == 0)
                bb = *(const short8*)(rhb + ((size_t)n * L + c0 + ccol) * DH + kh * 32 + lg * 8);
            else
                bb = ld8(KR, SW128(ccol, (kh * 32 + lg * 8) * 2));
            acc = __builtin_amdgcn_mfma_f32_16x16x32_bf16(a, bb, acc, 0, 0, 0);
        }
#pragma unroll
        for (int r2 = 0; r2 < 4; ++r2)
            BDp[(lg * 4 + r2) * BDP_ST + c0 + ccol] = f2h(acc[r2]);
        {
            const int col = tid >> 2, kq = (tid & 3) * 16;
            float s16 = 0.f;
#pragma unroll
            for (int kk = 0; kk < 16; kk += 8) {
                short8 qa = ld8(QV, SW128(16, (kq + kk) * 2));
                short8 ra;
                if constexpr (MODE == 0)
                    ra = *(const short8*)(rhb + ((size_t)n * L + c0 + col) * DH + kq + kk);
                else
                    ra = ld8(KR, SW128(col, (kq + kk) * 2));
#pragma unroll
                for (int e = 0; e < 8; ++e)
                    s16 = fmaf(bf2f((unsigned short)qa[e]), bf2f((unsigned short)ra[e]), s16);
            }
            s16 += __shfl_xor(s16, 1);
            s16 += __shfl_xor(s16, 2);
            if ((tid & 3) == 0) BDp[16 * BDP_ST + c0 + col] = f2h(s16);
        }
    }

    const int jloc = w * 16 + lr;
    __syncthreads();

    f32x4 pv = {0.f, 0.f, 0.f, 0.f};
    float dl[4] = {0.f, 0.f, 0.f, 0.f};
    float tmp[4][NJT];
#pragma unroll
    for (int jt = 0; jt < NJT; ++jt) {
        const int j0 = jt * 64;
        const int gj = j0 + jloc;
        const int cur = jt & 1;
        if constexpr (MODE == 1) {
            __syncthreads();
            for (int idx = tid; idx < 64 * 16; idx += 256) {
                const int jr = idx >> 4, d4 = (idx & 15) * 4;
                const size_t src = ((size_t)(j0 + jr) * BATCH + b) * DM + n * DH + d4;
                float4 kv = *(const float4*)(Kg + src);
                unsigned short* p = usp(KR, SW128(jr, d4 * 2));
                p[0] = f2bf(kv.x); p[1] = f2bf(kv.y); p[2] = f2bf(kv.z); p[3] = f2bf(kv.w);
                float4 vv4 = *(const float4*)(Vg + src);
                *usp(VT, SW128(d4 + 0, jr * 2)) = f2bf(vv4.x);
                *usp(VT, SW128(d4 + 1, jr * 2)) = f2bf(vv4.y);
                *usp(VT, SW128(d4 + 2, jr * 2)) = f2bf(vv4.z);
                *usp(VT, SW128(d4 + 3, jr * 2)) = f2bf(vv4.w);
            }
            __syncthreads();
        }
        f32x4 acc = {0.f, 0.f, 0.f, 0.f};
#pragma unroll
        for (int kh = 0; kh < 2; ++kh) {
            short8 a = ld8(QU, SW128(lr, (kh * 32 + lg * 8) * 2));
            short8 bb;
            if constexpr (MODE == 0)
                bb = *(const short8*)(Kbf + ((size_t)bn * L + gj) * DH + kh * 32 + lg * 8);
            else
                bb = ld8(KR, SW128(jloc, (kh * 32 + lg * 8) * 2));
            acc = __builtin_amdgcn_mfma_f32_16x16x32_bf16(a, bb, acc, 0, 0, 0);
        }
        const bool msk = mblk[gj] != 0;
#pragma unroll
        for (int r2 = 0; r2 < 4; ++r2) {
            const int il = lg * 4 + r2;
            const int gi = i0 + il;
            const int t = gj - gi;
            float bd = 0.f;
            if (t != 1) {
                const int c = (t <= 0) ? (L - 1 + t) : (t - 2);
                bd = h2f(BDp[(il + (t >= 1 ? 1 : 0)) * BDP_ST + c]);
            }
            float s = acc[r2] + bd;
            if (msk) s = -1e9f;
            const float wgt = __expf(fminf(s, 80.f));
            dl[r2] += wgt;
            tmp[r2][jt] = wgt;
            *usp(Wt[cur], SW128(il, jloc * 2)) = f2bf(wgt);
        }
        __syncthreads();
#pragma unroll
        for (int kh = 0; kh < 2; ++kh) {
            short8 a = ld8(Wt[cur], SW128(lr, (kh * 32 + lg * 8) * 2));
            short8 bb;
            if constexpr (MODE == 0)
                bb = *(const short8*)(Vtb + ((size_t)bn * DH + jloc) * L + j0 + kh * 32 + lg * 8);
            else
                bb = ld8(VT, SW128(jloc, (kh * 32 + lg * 8) * 2));
            pv = __builtin_amdgcn_mfma_f32_16x16x32_bf16(a, bb, pv, 0, 0, 0);
        }
    }

#pragma unroll
    for (int r2 = 0; r2 < 4; ++r2) {
        float d = dl[r2];
        d += __shfl_xor(d, 1); d += __shfl_xor(d, 2);
        d += __shfl_xor(d, 4); d += __shfl_xor(d, 8);
        if (lr == 0) denomP[w][lg * 4 + r2] = d;
    }
    __syncthreads();
    if (tid < 16)
        rdenom[tid] = 1.f / (denomP[0][tid] + denomP[1][tid] + denomP[2][tid] + denomP[3][tid]);
    __syncthreads();

#pragma unroll
    for (int r2 = 0; r2 < 4; ++r2) {
        const int il = lg * 4 + r2;
        out[((size_t)(i0 + il) * BATCH + b) * DM + n * DH + w * 16 + lr] = pv[r2] * rdenom[il];
    }
#pragma unroll
    for (int r2 = 0; r2 < 4; ++r2) {
        const int il = lg * 4 + r2;
        const float rs = rdenom[il] * (1.f / 16.f);
#pragma unroll
        for (int jt = 0; jt < NJT; ++jt)
            atomicAdd(wm_out + ((size_t)(i0 + il) * L + jt * 64 + jloc) * BATCH + b,
                      tmp[r2][jt] * rs);
    }
}

// ---------------------------------------------------------------------------
extern "C" void kernel_launch(void* const* d_in, const int* in_sizes, int n_in,
                              void* d_out, int out_size, void* d_ws, size_t ws_size,
                              hipStream_t stream)
{
    (void)in_sizes; (void)n_in; (void)out_size;
    const float* q   = (const float*)d_in[0];
    const float* K   = (const float*)d_in[1];
    const float* V   = (const float*)d_in[2];
    const unsigned char* mask = (const unsigned char*)d_in[3];
    const float* r   = (const float*)d_in[4];
    const float* u   = (const float*)d_in[5];
    const float* v   = (const float*)d_in[6];
    const float* Wr  = (const float*)d_in[7];
    const float* br  = (const float*)d_in[8];

    float* out = (float*)d_out;                    // (1024, 4, 1024)
    float* wm  = out + (size_t)L * BATCH * DM;     // (1024, 1024, 4)

    const size_t kvbytes = (size_t)BATCH * NH * L * DH * 2;   // 8 MB each
    const size_t rhbytes = (size_t)NH * L * DH * 2;           // 2 MB
    const size_t wmbytes = (size_t)BATCH * NH * L * L * 2;    // 134 MB
    const size_t rdbytes = (size_t)BATCH * NH * L * 4;        // 256 KB

    if (ws_size >= 2 * kvbytes + rhbytes + wmbytes + rdbytes) {
        unsigned short* Kbf = (unsigned short*)d_ws;
        unsigned short* Vtb = Kbf + kvbytes / 2;
        unsigned short* rhb = Vtb + kvbytes / 2;
        unsigned short* Wws = rhb + rhbytes / 2;
        float* rdeng = (float*)(Wws + wmbytes / 2);
        rh_gemm_mfma<<<dim3(16, 16), 256, 0, stream>>>(r, Wr, br, rhb);
        prepass_kernel<<<dim3(16, 4, 16), 256, 0, stream>>>(K, V, Kbf, Vtb);
        attn_fused<<<dim3(4096), 256, 0, stream>>>(
            q, Kbf, Vtb, mask, u, v, rhb, out, Wws, rdeng);
        wm_reduce_kernel<<<dim3(64, 4, 4), 256, 0, stream>>>(Wws, rdeng, wm);
    } else if (ws_size >= 2 * kvbytes + rhbytes) {
        hipMemsetAsync(wm, 0, (size_t)L * L * BATCH * sizeof(float), stream);
        unsigned short* Kbf = (unsigned short*)d_ws;
        unsigned short* Vtb = Kbf + kvbytes / 2;
        unsigned short* rhb = Vtb + kvbytes / 2;
        rh_gemm_mfma<<<dim3(16, 16), 256, 0, stream>>>(r, Wr, br, rhb);
        prepass_kernel<<<dim3(16, 4, 16), 256, 0, stream>>>(K, V, Kbf, Vtb);
        attn_legacy<0><<<dim3(64, 4, 16), 256, 0, stream>>>(
            q, Kbf, Vtb, mask, u, v, rhb, out, wm);
    } else {
        hipMemsetAsync(wm, 0, (size_t)L * L * BATCH * sizeof(float), stream);
        float* rhf = (float*)d_ws;
        rh_gemm_kernel<<<dim3(16, 16), 256, 0, stream>>>(r, Wr, br, rhf);
        attn_legacy<1><<<dim3(64, 4, 16), 256, 0, stream>>>(
            q, K, V, mask, u, v, rhf, out, wm);
    }
}